// Round 8
// baseline (707.105 us; speedup 1.0000x reference)
//
#include <hip/hip_runtime.h>
#include <hip/hip_bf16.h>
#include <hip/hip_cooperative_groups.h>

namespace cg = cooperative_groups;

typedef __hip_bfloat16 bf16;
typedef short s16x8 __attribute__((ext_vector_type(8)));
typedef float f32x4 __attribute__((ext_vector_type(4)));

#define N_NODES 50000
#define NPAD    50048          // multiple of 64
#define E_EDGES 600000
#define HID     128
#define HEADS   4
#define SCAN_B  196            // ceil(NPAD/256)

// virtual-block counts per phase
#define VB_ZERO 392            // ceil((2*NPAD+16)/256)
#define VB_IDX  2344           // ceil(E/256)
#define VB_WT   256
#define VB_CVT  (VB_IDX + VB_WT + 2)
#define VB_SCAN (SCAN_B + SCAN_B)
#define VB_PREP (SCAN_B + 2 + 64)
#define VB_SCAT 2344
#define VB_ROWS 782            // NPAD/64
#define VB_BIG  8824           // worst-case deg>16 nodes / 4
#define VB_QUAD 3125           // ceil(N/16)
#define VB_EDGE (VB_BIG + VB_QUAD)

// ---- float -> bf16 bits (RNE), finite inputs only ----
__device__ __forceinline__ unsigned short f2bf_bits(float f) {
  unsigned u = __float_as_uint(f);
  u += 0x7fffu + ((u >> 16) & 1u);
  return (unsigned short)(u >> 16);
}
__device__ __forceinline__ float bf2f(unsigned short b) {
  return __uint_as_float(((unsigned)b) << 16);
}
__device__ __forceinline__ float lo_f(unsigned v) { return __uint_as_float(v << 16); }
__device__ __forceinline__ float hi_f(unsigned v) { return __uint_as_float(v & 0xffff0000u); }
__device__ __forceinline__ float lrelu(float v) { return fmaxf(v, 0.2f * v); }
__device__ __forceinline__ float elu(float v) { return v > 0.f ? v : __expf(v) - 1.f; }

struct P8 { const void* src[8]; int dstoff[8]; int n[8]; };

struct MegaArgs {
  const void* x; const int* eidx; const int* etype;
  const void* w0; const void* w1; const void* pW0; const void* pW1;
  P8 tab; float* base;
  int* flags; unsigned short* xw; float4* qi4; float4* kj4; unsigned short* aggb;
  int* dstA; int* pk; int* eord; int* deg; int* cnt; int* bcnt;
  int* excl; int* rowstart; int* bsum; int* nq; int* nw;
  unsigned short* Wbt; unsigned short* pWTb2; unsigned short* qkt_hi; unsigned short* qkt_lo;
  float* Qf; float* Kf; float* cbf; float* pbf; float* bo2;
  void* dout;
};

// ====== shared phase bodies (identical arithmetic in mega and fallback) ======

__device__ __forceinline__ void phase_zero(const MegaArgs& a, int vb, int t) {
  int i = vb * 256 + t;
  if (i < 2 * NPAD + 16) a.deg[i] = 0;        // deg|cnt|bcnt contiguous
}

__device__ __forceinline__ void phase_detect(const MegaArgs& a, int t, int* dcnt) {
  if (t < 2) dcnt[t] = 0;
  __syncthreads();
  unsigned short v = ((const unsigned short*)a.x)[2 * t];
  int ex = (v >> 7) & 0xFF;
  if (ex < 119 || ex > 135) atomicAdd(&dcnt[0], 1);
  if (a.eidx[2 * t + 1] != 0) atomicAdd(&dcnt[1], 1);
  __syncthreads();
  if (t == 0) {
    a.flags[0] = (dcnt[0] > 64) ? 1 : 0;
    a.flags[1] = (dcnt[1] == 0) ? 1 : 0;
  }
}

__device__ __forceinline__ void phase_cvt(const MegaArgs& a, int vb, int t) {
  const int f0 = a.flags[0], f1 = a.flags[1];
  if (vb < VB_IDX) {
    int e = vb * 256 + t;
    if (e < E_EDGES) {
      int s, d, r;
      if (f1) {
        const long long* e64 = (const long long*)a.eidx;
        const long long* t64 = (const long long*)a.etype;
        s = (int)e64[e]; d = (int)e64[E_EDGES + e]; r = (int)t64[e];
      } else {
        s = a.eidx[e]; d = a.eidx[E_EDGES + e]; r = a.etype[e];
      }
      a.dstA[e] = d;
      a.pk[e] = s | (r << 16);
      atomicAdd(&a.deg[d], 1);
    }
  } else if (vb < VB_IDX + VB_WT) {
    int idx = (vb - VB_IDX) * 256 + t;
    int l = idx >> 15, rem = idx & 32767;
    int r = rem >> 14, i = (rem >> 7) & 127, o = rem & 127;
    const void* src = l ? a.w1 : a.w0;
    unsigned short v;
    if (f0) v = f2bf_bits(((const float*)src)[rem]);
    else    v = ((const unsigned short*)src)[rem];
    a.Wbt[(size_t)l * 2 * HID * HID + ((size_t)r * HID + o) * HID + i] = v;
  } else {
    int bb = vb - VB_IDX - VB_WT;             // 0..1
    for (int k = 0; k < 8; ++k) {
      int n = a.tab.n[k];
      for (int i = bb * 256 + t; i < n; i += 2 * 256) {
        float v = f0 ? ((const float*)a.tab.src[k])[i] : bf2f(((const unsigned short*)a.tab.src[k])[i]);
        a.base[a.tab.dstoff[k] + i] = v;
      }
    }
  }
}

__device__ __forceinline__ void phase_scan1b(const MegaArgs& a, int vb, int t, int lane, int* sm) {
  if (vb < SCAN_B) {
    int i = vb * 256 + t;
    int v = (i < NPAD) ? a.deg[i] : 0;
    sm[t] = v;
    __syncthreads();
#pragma unroll
    for (int off = 1; off < 256; off <<= 1) {
      int add = (t >= off) ? sm[t - off] : 0;
      __syncthreads();
      sm[t] += add;
      __syncthreads();
    }
    if (i < NPAD) a.excl[i] = sm[t] - v;
    if (t == 255) a.bsum[vb] = sm[255];
    __syncthreads();                          // sm reuse across loop iterations
  } else {
    int n = (vb - SCAN_B) * 256 + t;
    bool valid = n < N_NODES;
    int d = valid ? a.deg[n] : 0;
    bool isq = valid && (d <= 16);
    bool isw = valid && (d > 16);
    unsigned long long mq = __ballot(isq);
    unsigned long long mw = __ballot(isw);
    unsigned long long lower = (lane == 63) ? 0x7fffffffffffffffull : ((1ull << lane) - 1ull);
    int baseq = 0, basew = 0;
    int lq = (int)__ffsll(mq) - 1;
    int lw = (int)__ffsll(mw) - 1;
    if (mq && lane == lq) baseq = atomicAdd(&a.bcnt[0], (int)__popcll(mq));
    if (mw && lane == lw) basew = atomicAdd(&a.bcnt[1], (int)__popcll(mw));
    if (mq) baseq = __shfl(baseq, lq);
    if (mw) basew = __shfl(basew, lw);
    if (isq) a.nq[baseq + (int)__popcll(mq & lower)] = n;
    if (isw) a.nw[basew + (int)__popcll(mw & lower)] = n;
  }
}

__device__ __forceinline__ void phase_prep(const MegaArgs& a, int vb, int t, int wave, int lane, int* sm) {
  const int f0 = a.flags[0];
  if (vb < SCAN_B) {
    int v = (t < SCAN_B) ? a.bsum[t] : 0;
    sm[t] = v;
    __syncthreads();
#pragma unroll
    for (int off = 1; off < 256; off <<= 1) {
      int add = (t >= off) ? sm[t - off] : 0;
      __syncthreads();
      sm[t] += add;
      __syncthreads();
    }
    int bpre = (vb > 0) ? sm[vb - 1] : 0;
    int i = vb * 256 + t;
    if (i < NPAD) a.rowstart[i] = a.excl[i] + bpre;
    if (i == 0) a.rowstart[NPAD] = E_EDGES;
    __syncthreads();
  } else if (vb < SCAN_B + 2) {
    int idx = (vb - SCAN_B) * 256 + t;        // (l,r,i)
    int i = idx & 127, lr = idx >> 7, l = lr >> 1, r = (lr & 1);
    float aq[4] = {0.f, 0.f, 0.f, 0.f}, ak[4] = {0.f, 0.f, 0.f, 0.f};
    const unsigned short* Wb = a.Wbt + (size_t)lr * HID * HID;
    const float* Qp = a.Qf + l * HID * HEADS;
    const float* Kp = a.Kf + l * HID * HEADS;
    for (int j = 0; j < HID; ++j) {
      float w = bf2f(Wb[j * HID + i]);
      float4 q4 = *(const float4*)(Qp + j * 4);
      float4 k4 = *(const float4*)(Kp + j * 4);
      aq[0] += w * q4.x; aq[1] += w * q4.y; aq[2] += w * q4.z; aq[3] += w * q4.w;
      ak[0] += w * k4.x; ak[1] += w * k4.y; ak[2] += w * k4.z; ak[3] += w * k4.w;
    }
    size_t base = (size_t)l * 16 * HID;
#pragma unroll
    for (int h = 0; h < 4; ++h) {
      unsigned short qh = f2bf_bits(aq[h]);
      unsigned short kh = f2bf_bits(ak[h]);
      float qres = aq[h] - bf2f(qh);
      float kres = ak[h] - bf2f(kh);
      a.qkt_hi[base + (size_t)(r * 4 + h) * HID + i] = qh;
      a.qkt_lo[base + (size_t)(r * 4 + h) * HID + i] = f2bf_bits(qres);
      a.qkt_hi[base + (size_t)(8 + r * 4 + h) * HID + i] = kh;
      a.qkt_lo[base + (size_t)(8 + r * 4 + h) * HID + i] = f2bf_bits(kres);
    }
  } else {
    int ob = (vb - SCAN_B - 2) * 4 + wave;    // 0..255
    int o = ob & 127, l = ob >> 7;
    const void* pWraw = l ? a.pW1 : a.pW0;
    const float* cb = a.cbf + l * HID;
    float part = 0.f;
#pragma unroll
    for (int i = lane; i < HID; i += 64) {
      float w = f0 ? ((const float*)pWraw)[o * HID + i] : bf2f(((const unsigned short*)pWraw)[o * HID + i]);
      a.pWTb2[(size_t)l * HID * HID + o * HID + i] = f2bf_bits(w);
      part += cb[i] * w;
    }
#pragma unroll
    for (int off = 32; off > 0; off >>= 1) part += __shfl_xor(part, off);
    if (lane == 0) a.bo2[l * HID + o] = a.pbf[l * HID + o] + part;
  }
}

__device__ __forceinline__ void phase_scatter(const MegaArgs& a, int vb, int t) {
  int e = vb * 256 + t;
  if (e < E_EDGES) {
    int d = a.dstA[e];
    int pos = a.rowstart[d] + atomicAdd(&a.cnt[d], 1);
    a.eord[pos] = a.pk[e];
  }
}

// gemm body: As (64 rows bf16 in LDS) @ Wbt[r] -> xw, restaged through Cs.
__device__ __forceinline__ void gemm64_from_lds(unsigned short (*As)[136], unsigned short (*Cs)[136],
                                                const unsigned short* __restrict__ Wbt,
                                                unsigned short* __restrict__ xw, int row0,
                                                int wave, int lm, int q, int t) {
  const int r = wave >> 1, colb = (wave & 1) * 64;
  const unsigned short* Bt = Wbt + (size_t)r * HID * HID;
  s16x8 bfr[4][4];
#pragma unroll
  for (int kc = 0; kc < 4; ++kc) {
    const int ko = kc * 32 + q * 8;
#pragma unroll
    for (int ct = 0; ct < 4; ++ct)
      bfr[kc][ct] = *(const s16x8*)(Bt + (size_t)(colb + ct * 16 + lm) * HID + ko);
  }
  f32x4 acc[4][4];
#pragma unroll
  for (int aa = 0; aa < 4; ++aa)
#pragma unroll
    for (int c = 0; c < 4; ++c) { f32x4 z = {0.f, 0.f, 0.f, 0.f}; acc[aa][c] = z; }
#pragma unroll
  for (int kc = 0; kc < 4; ++kc) {
    const int ko = kc * 32 + q * 8;
#pragma unroll
    for (int rt = 0; rt < 4; ++rt) {
      s16x8 av = *(const s16x8*)&As[rt * 16 + lm][ko];
#pragma unroll
      for (int ct = 0; ct < 4; ++ct)
        acc[rt][ct] = __builtin_amdgcn_mfma_f32_16x16x32_bf16(av, bfr[kc][ct], acc[rt][ct], 0, 0, 0);
    }
  }
  __syncthreads();
#pragma unroll
  for (int rr = 0; rr < 2; ++rr) {
    if (r == rr) {
#pragma unroll
      for (int rt = 0; rt < 4; ++rt)
#pragma unroll
        for (int i = 0; i < 4; ++i) {
          int rloc = rt * 16 + q * 4 + i;
#pragma unroll
          for (int ct = 0; ct < 4; ++ct)
            Cs[rloc][colb + ct * 16 + lm] = f2bf_bits(acc[rt][ct][i]);
        }
    }
    __syncthreads();
    unsigned short* dst = xw + ((size_t)rr * NPAD + row0) * HID;
#pragma unroll
    for (int j = 0; j < 4; ++j) {
      int idx = j * 256 + t;                  // 1024 16B units
      int rw = idx >> 4, cb8 = (idx & 15) * 8;
      if (row0 + rw < N_NODES)
        *(s16x8*)(dst + (size_t)rw * HID + cb8) = *(const s16x8*)&Cs[rw][cb8];
    }
    __syncthreads();
  }
}

// qk body: wave w handles rows [16w,16w+16) of As; writes qi4/kj4.
__device__ __forceinline__ void qk16_from_lds(unsigned short (*As)[136], unsigned short (*Cs)[136],
                                              const unsigned short* __restrict__ qkt_hi,
                                              const unsigned short* __restrict__ qkt_lo,
                                              float4* __restrict__ qi4, float4* __restrict__ kj4,
                                              int row0, int wave, int lane, int lm, int q) {
  s16x8 bhi[4], blo[4], af[4];
#pragma unroll
  for (int kc = 0; kc < 4; ++kc) {
    const int ko = kc * 32 + q * 8;
    bhi[kc] = *(const s16x8*)(qkt_hi + (size_t)lm * HID + ko);
    blo[kc] = *(const s16x8*)(qkt_lo + (size_t)lm * HID + ko);
    af[kc]  = *(const s16x8*)&As[wave * 16 + lm][ko];
  }
  f32x4 acc = {0.f, 0.f, 0.f, 0.f};
#pragma unroll
  for (int kc = 0; kc < 4; ++kc) {
    acc = __builtin_amdgcn_mfma_f32_16x16x32_bf16(af[kc], bhi[kc], acc, 0, 0, 0);
    acc = __builtin_amdgcn_mfma_f32_16x16x32_bf16(af[kc], blo[kc], acc, 0, 0, 0);
  }
  float (*Fs)[16][17] = (float(*)[16][17])&Cs[0][0];   // 4*16*17*4 = 17408 B
#pragma unroll
  for (int i = 0; i < 4; ++i)
    Fs[wave][lm][q * 4 + i] = acc[i];
  __syncthreads();
  if (lane < 16) {
    int n = row0 + wave * 16 + lane;
    if (n < N_NODES) {
      float4 v;
      v.x = Fs[wave][0][lane];  v.y = Fs[wave][1][lane];  v.z = Fs[wave][2][lane];  v.w = Fs[wave][3][lane];
      qi4[n] = v;
      v.x = Fs[wave][4][lane];  v.y = Fs[wave][5][lane];  v.z = Fs[wave][6][lane];  v.w = Fs[wave][7][lane];
      qi4[NPAD + n] = v;
      v.x = Fs[wave][8][lane];  v.y = Fs[wave][9][lane];  v.z = Fs[wave][10][lane]; v.w = Fs[wave][11][lane];
      kj4[n] = v;
      v.x = Fs[wave][12][lane]; v.y = Fs[wave][13][lane]; v.z = Fs[wave][14][lane]; v.w = Fs[wave][15][lane];
      kj4[NPAD + n] = v;
    }
  }
  __syncthreads();
}

__device__ __forceinline__ void phase_l0(const MegaArgs& a, int vb, int t, int wave, int lane, int lm, int q,
                                         unsigned short (*As)[136], unsigned short (*Cs)[136]) {
  const int row0 = vb * 64;
  if (a.flags[0]) {
    const float* xf = (const float*)a.x;
#pragma unroll
    for (int j = 0; j < 4; ++j) {
      int idx = j * 256 + t;
      int rw = idx >> 4, cb8 = (idx & 15) * 8;
      s16x8 o = {0, 0, 0, 0, 0, 0, 0, 0};
      if (row0 + rw < N_NODES) {
        const float4* s4 = (const float4*)(xf + (size_t)(row0 + rw) * HID + cb8);
        float4 aa = s4[0], b = s4[1];
        o[0] = (short)f2bf_bits(aa.x); o[1] = (short)f2bf_bits(aa.y);
        o[2] = (short)f2bf_bits(aa.z); o[3] = (short)f2bf_bits(aa.w);
        o[4] = (short)f2bf_bits(b.x);  o[5] = (short)f2bf_bits(b.y);
        o[6] = (short)f2bf_bits(b.z);  o[7] = (short)f2bf_bits(b.w);
      }
      *(s16x8*)&As[rw][cb8] = o;
    }
  } else {
    const unsigned short* xb = (const unsigned short*)a.x;
#pragma unroll
    for (int j = 0; j < 4; ++j) {
      int idx = j * 256 + t;
      int rw = idx >> 4, cb8 = (idx & 15) * 8;
      s16x8 o = {0, 0, 0, 0, 0, 0, 0, 0};
      if (row0 + rw < N_NODES)
        o = *(const s16x8*)(xb + (size_t)(row0 + rw) * HID + cb8);
      *(s16x8*)&As[rw][cb8] = o;
    }
  }
  __syncthreads();
  gemm64_from_lds(As, Cs, a.Wbt, a.xw, row0, wave, lm, q, t);
  qk16_from_lds(As, Cs, a.qkt_hi, a.qkt_lo, a.qi4, a.kj4, row0, wave, lane, lm, q);
}

__device__ __forceinline__ void phase_mid(const MegaArgs& a, int vb, int t, int wave, int lane, int lm, int q,
                                          unsigned short (*As)[136], unsigned short (*Cs)[136]) {
  const int row0 = vb * 64;
  const int h = wave >> 1;
  const int colb = (wave & 1) * 64;
  s16x8 bfr[4][4];
#pragma unroll
  for (int kc = 0; kc < 4; ++kc) {
    const int ko = kc * 32 + q * 8;
#pragma unroll
    for (int ct = 0; ct < 4; ++ct)
      bfr[kc][ct] = *(const s16x8*)(a.pWTb2 + (size_t)(colb + ct * 16 + lm) * HID + ko);
  }
  const unsigned short* gsrc = a.aggb + (size_t)row0 * HID;
#pragma unroll
  for (int j = 0; j < 4; ++j) {
    int idx = j * 256 + t;
    *(s16x8*)&As[idx >> 4][(idx & 15) * 8] = *(const s16x8*)(gsrc + idx * 8);
  }
  __syncthreads();
  f32x4 pacc[2][4];
#pragma unroll
  for (int aa = 0; aa < 2; ++aa)
#pragma unroll
    for (int c = 0; c < 4; ++c) { f32x4 z = {0.f, 0.f, 0.f, 0.f}; pacc[aa][c] = z; }
#pragma unroll
  for (int kc = 0; kc < 4; ++kc) {
    const int ko = kc * 32 + q * 8;
#pragma unroll
    for (int rt = 0; rt < 2; ++rt) {
      s16x8 av = *(const s16x8*)&As[(2 * h + rt) * 16 + lm][ko];
#pragma unroll
      for (int ct = 0; ct < 4; ++ct)
        pacc[rt][ct] = __builtin_amdgcn_mfma_f32_16x16x32_bf16(av, bfr[kc][ct], pacc[rt][ct], 0, 0, 0);
    }
  }
  __syncthreads();
#pragma unroll
  for (int rt = 0; rt < 2; ++rt)
#pragma unroll
    for (int i = 0; i < 4; ++i) {
      int rloc = (2 * h + rt) * 16 + q * 4 + i;
#pragma unroll
      for (int ct = 0; ct < 4; ++ct) {
        int o = colb + ct * 16 + lm;
        As[rloc][o] = f2bf_bits(elu(pacc[rt][ct][i] + a.bo2[o]));
      }
    }
  __syncthreads();
  const unsigned short* Wbt1 = a.Wbt + (size_t)2 * HID * HID;
  gemm64_from_lds(As, Cs, Wbt1, a.xw, row0, wave, lm, q, t);
  qk16_from_lds(As, Cs, a.qkt_hi + (size_t)16 * HID, a.qkt_lo + (size_t)16 * HID,
                a.qi4, a.kj4, row0, wave, lane, lm, q);
}

__device__ __forceinline__ void phase_final(const MegaArgs& a, int vb, int t, int wave, int lane, int lm, int q,
                                            unsigned short (*As)[136]) {
  const int row0 = vb * 64;
  const int h = wave >> 1;
  const int colb = (wave & 1) * 64;
  const unsigned short* pWT1 = a.pWTb2 + (size_t)HID * HID;
  const float* bo1 = a.bo2 + HID;
  s16x8 bfr[4][4];
#pragma unroll
  for (int kc = 0; kc < 4; ++kc) {
    const int ko = kc * 32 + q * 8;
#pragma unroll
    for (int ct = 0; ct < 4; ++ct)
      bfr[kc][ct] = *(const s16x8*)(pWT1 + (size_t)(colb + ct * 16 + lm) * HID + ko);
  }
  const unsigned short* gsrc = a.aggb + (size_t)row0 * HID;
#pragma unroll
  for (int j = 0; j < 4; ++j) {
    int idx = j * 256 + t;
    *(s16x8*)&As[idx >> 4][(idx & 15) * 8] = *(const s16x8*)(gsrc + idx * 8);
  }
  __syncthreads();
  f32x4 acc[2][4];
#pragma unroll
  for (int aa = 0; aa < 2; ++aa)
#pragma unroll
    for (int c = 0; c < 4; ++c) { f32x4 z = {0.f, 0.f, 0.f, 0.f}; acc[aa][c] = z; }
#pragma unroll
  for (int kc = 0; kc < 4; ++kc) {
    const int ko = kc * 32 + q * 8;
#pragma unroll
    for (int rt = 0; rt < 2; ++rt) {
      s16x8 av = *(const s16x8*)&As[(2 * h + rt) * 16 + lm][ko];
#pragma unroll
      for (int ct = 0; ct < 4; ++ct)
        acc[rt][ct] = __builtin_amdgcn_mfma_f32_16x16x32_bf16(av, bfr[kc][ct], acc[rt][ct], 0, 0, 0);
    }
  }
  __syncthreads();
  if (!a.flags[0]) {
    unsigned short* dstp = (unsigned short*)a.dout;
#pragma unroll
    for (int rt = 0; rt < 2; ++rt)
#pragma unroll
      for (int i = 0; i < 4; ++i) {
        int rloc = (2 * h + rt) * 16 + q * 4 + i;
#pragma unroll
        for (int ct = 0; ct < 4; ++ct) {
          int o = colb + ct * 16 + lm;
          As[rloc][o] = f2bf_bits(elu(acc[rt][ct][i] + bo1[o]));
        }
      }
    __syncthreads();
#pragma unroll
    for (int j = 0; j < 4; ++j) {
      int idx = j * 256 + t;
      int rw = idx >> 4, cb8 = (idx & 15) * 8;
      if (row0 + rw < N_NODES)
        *(s16x8*)(dstp + (size_t)(row0 + rw) * HID + cb8) = *(const s16x8*)&As[rw][cb8];
    }
    __syncthreads();
  } else {
    float* fdst = (float*)a.dout;
    float (*Fs)[132] = (float(*)[132])&As[0][0];   // 32*132*4 = 16896 B
#pragma unroll
    for (int h2 = 0; h2 < 2; ++h2) {
      if (h == h2) {
#pragma unroll
        for (int rt = 0; rt < 2; ++rt)
#pragma unroll
          for (int i = 0; i < 4; ++i) {
            int rloc = rt * 16 + q * 4 + i;
#pragma unroll
            for (int ct = 0; ct < 4; ++ct) {
              int o = colb + ct * 16 + lm;
              Fs[rloc][o] = elu(acc[rt][ct][i] + bo1[o]);
            }
          }
      }
      __syncthreads();
#pragma unroll
      for (int j = 0; j < 4; ++j) {
        int idx = j * 256 + t;
        int rw = idx >> 5, cb4 = (idx & 31) * 4;
        if (row0 + h2 * 32 + rw < N_NODES)
          *(float4*)(fdst + (size_t)(row0 + h2 * 32 + rw) * HID + cb4) = *(const float4*)&Fs[rw][cb4];
      }
      __syncthreads();
    }
  }
}

// edge phase body for one virtual block (big-first ordering)
__device__ __forceinline__ void edge_vb(const MegaArgs& a, int vb, volatile float* wbuf,
                                        int wave, int lane) {
  const float4* qi4 = a.qi4;
  const float4* kj4 = a.kj4;
  const unsigned short* xw = a.xw;
  if (vb >= VB_BIG) {
    // ---- quad: 4 nodes/wave, 16 lanes/node, 8 ch/lane ----
    const int g = lane >> 4, li = lane & 15;
    const int idx = (vb - VB_BIG) * 16 + wave * 4 + g;
    const int cq = a.bcnt[0];
    const bool act = idx < cq;
    const int n = act ? a.nq[idx] : 0;
    const int start = a.rowstart[n];
    const int dg = act ? (a.rowstart[n + 1] - start) : 0;
    int p = 0;
    float w0 = 0.f, w1 = 0.f, w2 = 0.f, w3 = 0.f;
    if (li < dg) {
      p = a.eord[start + li];
      int s = p & 0xffff, r = p >> 16;
      float4 k4 = kj4[r ? (NPAD + s) : s];
      float4 q4 = r ? qi4[NPAD + n] : qi4[n];
      w0 = __expf(fminf(lrelu(q4.x + k4.x), 85.f));
      w1 = __expf(fminf(lrelu(q4.y + k4.y), 85.f));
      w2 = __expf(fminf(lrelu(q4.z + k4.z), 85.f));
      w3 = __expf(fminf(lrelu(q4.w + k4.w), 85.f));
    }
    const int wg = (wave << 2) | g;
    volatile float* wls = &wbuf[wg * 68];     // [4][17]
    wls[0 * 17 + li] = w0; wls[1 * 17 + li] = w1;
    wls[2 * 17 + li] = w2; wls[3 * 17 + li] = w3;
    float s0 = w0, s1 = w1, s2 = w2, s3 = w3;
#pragma unroll
    for (int off = 8; off > 0; off >>= 1) {
      s0 += __shfl_xor(s0, off); s1 += __shfl_xor(s1, off);
      s2 += __shfl_xor(s2, off); s3 += __shfl_xor(s3, off);
    }
    const int hh = li >> 2;
    float ssel = hh == 0 ? s0 : hh == 1 ? s1 : hh == 2 ? s2 : s3;
    float a0 = 0.f, a1 = 0.f, a2 = 0.f, a3 = 0.f, a4 = 0.f, a5 = 0.f, a6 = 0.f, a7 = 0.f;
    volatile const float* wrh = &wls[hh * 17];
    const int co = li * 8;
    const int gbase = lane & 48;
#pragma unroll 1
    for (int e0 = 0; e0 < dg; e0 += 4) {
      int pe[4];
      uint4 v[4];
#pragma unroll
      for (int u = 0; u < 4; ++u) {
        int e = e0 + u;
        pe[u] = __shfl(p, gbase + (e < dg ? e : 0));
      }
#pragma unroll
      for (int u = 0; u < 4; ++u)
        v[u] = *(const uint4*)(xw + ((size_t)((pe[u] & 0xffff) + (pe[u] >> 16) * NPAD) << 7) + co);
#pragma unroll
      for (int u = 0; u < 4; ++u) {
        int e = e0 + u;
        float we = (e < dg) ? wrh[e] : 0.f;
        a0 = fmaf(lo_f(v[u].x), we, a0); a1 = fmaf(hi_f(v[u].x), we, a1);
        a2 = fmaf(lo_f(v[u].y), we, a2); a3 = fmaf(hi_f(v[u].y), we, a3);
        a4 = fmaf(lo_f(v[u].z), we, a4); a5 = fmaf(hi_f(v[u].z), we, a5);
        a6 = fmaf(lo_f(v[u].w), we, a6); a7 = fmaf(hi_f(v[u].w), we, a7);
      }
    }
    if (act) {
      float inv = 1.f / (ssel + 1e-16f);
      uint4 o;
      o.x = (unsigned)f2bf_bits(a0 * inv) | ((unsigned)f2bf_bits(a1 * inv) << 16);
      o.y = (unsigned)f2bf_bits(a2 * inv) | ((unsigned)f2bf_bits(a3 * inv) << 16);
      o.z = (unsigned)f2bf_bits(a4 * inv) | ((unsigned)f2bf_bits(a5 * inv) << 16);
      o.w = (unsigned)f2bf_bits(a6 * inv) | ((unsigned)f2bf_bits(a7 * inv) << 16);
      *(uint4*)(a.aggb + ((size_t)n << 7) + co) = o;
    }
  } else {
    // ---- big: one wave per node ----
    const int idx = vb * 4 + wave;
    const int cw = a.bcnt[1];
    if (idx < cw) {
      const int n = a.nw[idx];
      unsigned* outp = (unsigned*)(a.aggb + ((size_t)n << 7)) + lane;
      const int start = a.rowstart[n];
      const int deg = a.rowstart[n + 1] - start;
      const int hh = lane >> 4;
      const int ch2 = lane << 1;
      float2 acc = {0.f, 0.f};
      float ssel;
      volatile float* wls = &wbuf[wave * 288];  // [4][72]
      if (deg <= 64) {
        int p = 0;
        float w0 = 0.f, w1 = 0.f, w2 = 0.f, w3 = 0.f;
        if (lane < deg) {
          p = a.eord[start + lane];
          int s = p & 0xffff, r = p >> 16;
          float4 k4 = kj4[r ? (NPAD + s) : s];
          float4 q4 = r ? qi4[NPAD + n] : qi4[n];
          w0 = __expf(fminf(lrelu(q4.x + k4.x), 85.f));
          w1 = __expf(fminf(lrelu(q4.y + k4.y), 85.f));
          w2 = __expf(fminf(lrelu(q4.z + k4.z), 85.f));
          w3 = __expf(fminf(lrelu(q4.w + k4.w), 85.f));
        }
        float s0 = w0, s1 = w1, s2 = w2, s3 = w3;
#pragma unroll
        for (int off = 32; off > 0; off >>= 1) {
          s0 += __shfl_xor(s0, off); s1 += __shfl_xor(s1, off);
          s2 += __shfl_xor(s2, off); s3 += __shfl_xor(s3, off);
        }
        ssel = hh == 0 ? s0 : hh == 1 ? s1 : hh == 2 ? s2 : s3;
        wls[0 * 72 + lane] = w0;
        wls[1 * 72 + lane] = w1;
        wls[2 * 72 + lane] = w2;
        wls[3 * 72 + lane] = w3;
        volatile const float* wrh = &wls[hh * 72];
        const int degp = (deg + 15) & ~15;
#pragma unroll 1
        for (int e = 0; e < degp; e += 16) {
          int pp[16];
          unsigned vv[16];
#pragma unroll
          for (int u = 0; u < 16; ++u)
            pp[u] = __builtin_amdgcn_readlane(p, e + u);
#pragma unroll
          for (int u = 0; u < 16; ++u)
            vv[u] = *(const unsigned*)(xw + ((size_t)((pp[u] & 0xffff) + (pp[u] >> 16) * NPAD) << 7) + ch2);
#pragma unroll
          for (int u = 0; u < 16; ++u) {
            float we = wrh[e + u];
            acc.x = fmaf(lo_f(vv[u]), we, acc.x);
            acc.y = fmaf(hi_f(vv[u]), we, acc.y);
          }
        }
      } else {
        const float4 q0 = qi4[n], q1 = qi4[NPAD + n];
        float4 m = make_float4(-1e30f, -1e30f, -1e30f, -1e30f);
        for (int e = start; e < start + deg; ++e) {
          int pe = a.eord[e];
          int s = pe & 0xffff, r = pe >> 16;
          float4 k4 = kj4[(size_t)r * NPAD + s];
          float4 q4 = r ? q1 : q0;
          m.x = fmaxf(m.x, lrelu(q4.x + k4.x)); m.y = fmaxf(m.y, lrelu(q4.y + k4.y));
          m.z = fmaxf(m.z, lrelu(q4.z + k4.z)); m.w = fmaxf(m.w, lrelu(q4.w + k4.w));
        }
        float4 sv = make_float4(0.f, 0.f, 0.f, 0.f);
        for (int e = start; e < start + deg; ++e) {
          int pe = a.eord[e];
          int s = pe & 0xffff, r = pe >> 16;
          float4 k4 = kj4[(size_t)r * NPAD + s];
          float4 q4 = r ? q1 : q0;
          float w0 = __expf(lrelu(q4.x + k4.x) - m.x);
          float w1 = __expf(lrelu(q4.y + k4.y) - m.y);
          float w2 = __expf(lrelu(q4.z + k4.z) - m.z);
          float w3 = __expf(lrelu(q4.w + k4.w) - m.w);
          sv.x += w0; sv.y += w1; sv.z += w2; sv.w += w3;
          float we = hh == 0 ? w0 : hh == 1 ? w1 : hh == 2 ? w2 : w3;
          unsigned v = *(const unsigned*)(xw + (((size_t)r * NPAD + s) << 7) + ch2);
          acc.x = fmaf(lo_f(v), we, acc.x);
          acc.y = fmaf(hi_f(v), we, acc.y);
        }
        ssel = hh == 0 ? sv.x : hh == 1 ? sv.y : hh == 2 ? sv.z : sv.w;
      }
      float inv = 1.f / (ssel + 1e-16f);
      *outp = (unsigned)f2bf_bits(acc.x * inv) | ((unsigned)f2bf_bits(acc.y * inv) << 16);
    }
  }
}

// ====== mega kernel (cooperative) ======
__global__ __launch_bounds__(256, 2) void mega_kernel(MegaArgs a) {
  cg::grid_group grid = cg::this_grid();
  __shared__ char smem_raw[34816];
  unsigned short (*As)[136] = (unsigned short(*)[136])smem_raw;
  unsigned short (*Cs)[136] = (unsigned short(*)[136])(smem_raw + 17408);
  const int t = threadIdx.x;
  const int wave = t >> 6, lane = t & 63;
  const int lm = lane & 15, q = lane >> 4;
  const int NB = gridDim.x, bid = blockIdx.x;

  for (int vb = bid; vb < VB_ZERO; vb += NB) phase_zero(a, vb, t);
  if (bid == 0) phase_detect(a, t, (int*)smem_raw);
  grid.sync();
  for (int vb = bid; vb < VB_CVT; vb += NB) phase_cvt(a, vb, t);
  grid.sync();
  for (int vb = bid; vb < VB_SCAN; vb += NB) phase_scan1b(a, vb, t, lane, (int*)smem_raw);
  grid.sync();
  for (int vb = bid; vb < VB_PREP; vb += NB) phase_prep(a, vb, t, wave, lane, (int*)smem_raw);
  grid.sync();
  for (int vb = bid; vb < VB_SCAT; vb += NB) phase_scatter(a, vb, t);
  grid.sync();
  for (int vb = bid; vb < VB_ROWS; vb += NB) phase_l0(a, vb, t, wave, lane, lm, q, As, Cs);
  grid.sync();
  for (int vb = bid; vb < VB_EDGE; vb += NB) edge_vb(a, vb, (volatile float*)smem_raw, wave, lane);
  grid.sync();
  for (int vb = bid; vb < VB_ROWS; vb += NB) phase_mid(a, vb, t, wave, lane, lm, q, As, Cs);
  grid.sync();
  for (int vb = bid; vb < VB_EDGE; vb += NB) edge_vb(a, vb, (volatile float*)smem_raw, wave, lane);
  grid.sync();
  for (int vb = bid; vb < VB_ROWS; vb += NB) phase_final(a, vb, t, wave, lane, lm, q, As);
}

// ====== fallback kernels (one dispatch per phase, verified R5 structure) ======
__global__ __launch_bounds__(256) void k_zero(MegaArgs a) {
  __shared__ int dcnt[2];
  phase_zero(a, blockIdx.x, threadIdx.x);
  if (blockIdx.x == 0) phase_detect(a, threadIdx.x, dcnt);
}
__global__ __launch_bounds__(256) void k_cvt(MegaArgs a) {
  phase_cvt(a, blockIdx.x, threadIdx.x);
}
__global__ __launch_bounds__(256) void k_scan1b(MegaArgs a) {
  __shared__ int sm[256];
  phase_scan1b(a, blockIdx.x, threadIdx.x, threadIdx.x & 63, sm);
}
__global__ __launch_bounds__(256) void k_prep(MegaArgs a) {
  __shared__ int sm[256];
  phase_prep(a, blockIdx.x, threadIdx.x, threadIdx.x >> 6, threadIdx.x & 63, sm);
}
__global__ __launch_bounds__(256) void k_scatter(MegaArgs a) {
  phase_scatter(a, blockIdx.x, threadIdx.x);
}
__global__ __launch_bounds__(256) void k_l0(MegaArgs a) {
  __shared__ unsigned short As[64][136];
  __shared__ unsigned short Cs[64][136];
  const int t = threadIdx.x, wave = t >> 6, lane = t & 63;
  phase_l0(a, blockIdx.x, t, wave, lane, lane & 15, lane >> 4, As, Cs);
}
__global__ __launch_bounds__(256) void k_edge(MegaArgs a) {
  __shared__ volatile float wbuf[1152];
  phase_zero, (void)0;
  edge_vb(a, blockIdx.x, wbuf, threadIdx.x >> 6, threadIdx.x & 63);
}
__global__ __launch_bounds__(256) void k_mid(MegaArgs a) {
  __shared__ unsigned short As[64][136];
  __shared__ unsigned short Cs[64][136];
  const int t = threadIdx.x, wave = t >> 6, lane = t & 63;
  phase_mid(a, blockIdx.x, t, wave, lane, lane & 15, lane >> 4, As, Cs);
}
__global__ __launch_bounds__(256) void k_final(MegaArgs a) {
  __shared__ unsigned short As[64][136];
  const int t = threadIdx.x, wave = t >> 6, lane = t & 63;
  phase_final(a, blockIdx.x, t, wave, lane, lane & 15, lane >> 4, As);
}

extern "C" void kernel_launch(void* const* d_in, const int* in_sizes, int n_in,
                              void* d_out, int out_size, void* d_ws, size_t ws_size,
                              hipStream_t stream) {
  const int iW[2] = {3, 9}, iQ[2] = {4, 10}, iK[2] = {5, 11}, icb[2] = {6, 12}, ipW[2] = {7, 13}, ipb[2] = {8, 14};

  float* ws = (float*)d_ws;
  size_t off = 0;
  int*   flags = (int*)(ws + off); off += 16;
  unsigned short* xw   = (unsigned short*)(ws + off); off += (size_t)NPAD * HID;       // [2][NPAD][128] bf16
  float* qi   = ws + off; off += (size_t)2 * NPAD * HEADS;
  float* kj   = ws + off; off += (size_t)2 * NPAD * HEADS;
  unsigned short* aggb = (unsigned short*)(ws + off); off += (size_t)NPAD * HID / 2;
  int* dstA = (int*)(ws + off); off += E_EDGES;
  int* pk   = (int*)(ws + off); off += E_EDGES;
  int* eord = (int*)(ws + off); off += E_EDGES;
  int* deg  = (int*)(ws + off); off += NPAD;        // deg|cnt|bcnt contiguous for one zero pass
  int* cnt  = (int*)(ws + off); off += NPAD;
  int* bcnt = (int*)(ws + off); off += 16;
  int* excl = (int*)(ws + off); off += NPAD;
  int* rowstart = (int*)(ws + off); off += NPAD + 16;
  int* bsum  = (int*)(ws + off); off += 256;
  int* nq   = (int*)(ws + off); off += NPAD;
  int* nwl  = (int*)(ws + off); off += NPAD;
  unsigned short* Wbt   = (unsigned short*)(ws + off); off += (size_t)2 * 2 * HID * HID / 2;
  unsigned short* pWTb2 = (unsigned short*)(ws + off); off += (size_t)2 * HID * HID / 2;
  unsigned short* qkt_hi = (unsigned short*)(ws + off); off += (size_t)2 * 16 * HID / 2;
  unsigned short* qkt_lo = (unsigned short*)(ws + off); off += (size_t)2 * 16 * HID / 2;
  float* Qf  = ws + off; off += 2 * HID * HEADS;
  float* Kf  = ws + off; off += 2 * HID * HEADS;
  float* cbf = ws + off; off += 2 * HID;
  float* pbf = ws + off; off += 2 * HID;
  float* bo2 = ws + off; off += 2 * HID;

  MegaArgs a;
  a.x = d_in[0]; a.eidx = (const int*)d_in[1]; a.etype = (const int*)d_in[2];
  a.w0 = d_in[iW[0]]; a.w1 = d_in[iW[1]]; a.pW0 = d_in[ipW[0]]; a.pW1 = d_in[ipW[1]];
  for (int l = 0; l < 2; ++l) {
    a.tab.src[l * 4 + 0] = d_in[iQ[l]];  a.tab.dstoff[l * 4 + 0] = (int)(Qf - ws) + l * HID * HEADS;  a.tab.n[l * 4 + 0] = HID * HEADS;
    a.tab.src[l * 4 + 1] = d_in[iK[l]];  a.tab.dstoff[l * 4 + 1] = (int)(Kf - ws) + l * HID * HEADS;  a.tab.n[l * 4 + 1] = HID * HEADS;
    a.tab.src[l * 4 + 2] = d_in[icb[l]]; a.tab.dstoff[l * 4 + 2] = (int)(cbf - ws) + l * HID;         a.tab.n[l * 4 + 2] = HID;
    a.tab.src[l * 4 + 3] = d_in[ipb[l]]; a.tab.dstoff[l * 4 + 3] = (int)(pbf - ws) + l * HID;         a.tab.n[l * 4 + 3] = HID;
  }
  a.base = ws;
  a.flags = flags; a.xw = xw; a.qi4 = (float4*)qi; a.kj4 = (float4*)kj; a.aggb = aggb;
  a.dstA = dstA; a.pk = pk; a.eord = eord; a.deg = deg; a.cnt = cnt; a.bcnt = bcnt;
  a.excl = excl; a.rowstart = rowstart; a.bsum = bsum; a.nq = nq; a.nw = nwl;
  a.Wbt = Wbt; a.pWTb2 = pWTb2; a.qkt_hi = qkt_hi; a.qkt_lo = qkt_lo;
  a.Qf = Qf; a.Kf = Kf; a.cbf = cbf; a.pbf = pbf; a.bo2 = bo2;
  a.dout = d_out;

  // ---- cooperative attempt: query real occupancy, verify, fall back on any error ----
  static int s_cus = 0;
  static int s_blocks_per_cu = -1;            // -1 = unqueried, 0 = coop disabled
  if (s_blocks_per_cu == -1) {
    hipDeviceProp_t prop;
    if (hipGetDeviceProperties(&prop, 0) == hipSuccess && prop.multiProcessorCount > 0)
      s_cus = prop.multiProcessorCount;
    else
      s_cus = 256;
    int mb = 0;
    if (hipOccupancyMaxActiveBlocksPerMultiprocessor(&mb, mega_kernel, 256, 0) != hipSuccess) mb = 0;
    s_blocks_per_cu = (mb > 0) ? mb : 0;
  }
  if (s_blocks_per_cu > 0) {
    int grid = s_blocks_per_cu * s_cus;
    if (grid > 1024) grid = 1024;
    void* kargs[] = { (void*)&a };
    hipError_t e = hipLaunchCooperativeKernel(mega_kernel, dim3(grid), dim3(256), kargs, 0u, stream);
    if (e == hipSuccess) return;
    s_blocks_per_cu = 0;                      // don't retry coop (protects graph capture)
  }

  // ---- fallback: verified R5-equivalent dispatch sequence ----
  k_zero<<<VB_ZERO, 256, 0, stream>>>(a);
  k_cvt<<<VB_CVT, 256, 0, stream>>>(a);
  k_scan1b<<<VB_SCAN, 256, 0, stream>>>(a);
  k_prep<<<VB_PREP, 256, 0, stream>>>(a);
  k_scatter<<<VB_SCAT, 256, 0, stream>>>(a);
  k_l0<<<VB_ROWS, 256, 0, stream>>>(a);
  k_edge<<<VB_EDGE, 256, 0, stream>>>(a);
  k_mid<<<VB_ROWS, 256, 0, stream>>>(a);
  k_edge<<<VB_EDGE, 256, 0, stream>>>(a);
  k_final<<<VB_ROWS, 256, 0, stream>>>(a);
}

// Round 9
// 334.691 us; speedup vs baseline: 2.1127x; 2.1127x over previous
//
#include <hip/hip_runtime.h>
#include <hip/hip_bf16.h>

typedef __hip_bfloat16 bf16;
typedef short s16x8 __attribute__((ext_vector_type(8)));
typedef float f32x4 __attribute__((ext_vector_type(4)));

#define N_NODES 50000
#define NPAD    50048          // multiple of 64
#define E_EDGES 600000
#define HID     128
#define HEADS   4
#define SCAN_B  196            // ceil(NPAD/256)

// block counts
#define VB_ZERO 392            // ceil((2*NPAD+16)/256)
#define VB_IDX  2344           // ceil(E/256)
#define VB_WT   256
#define VB_CVT  (VB_IDX + VB_WT + 2)
#define VB_SCAT 2344
#define VB_ROWS 782            // NPAD/64
#define VB_BIG  8824           // worst-case deg>16 nodes / 4
#define VB_QUAD 3125           // ceil(N/16)
#define VB_EDGE (VB_BIG + VB_QUAD)

// ---- float -> bf16 bits (RNE), finite inputs only ----
__device__ __forceinline__ unsigned short f2bf_bits(float f) {
  unsigned u = __float_as_uint(f);
  u += 0x7fffu + ((u >> 16) & 1u);
  return (unsigned short)(u >> 16);
}
__device__ __forceinline__ float bf2f(unsigned short b) {
  return __uint_as_float(((unsigned)b) << 16);
}
__device__ __forceinline__ float lo_f(unsigned v) { return __uint_as_float(v << 16); }
__device__ __forceinline__ float hi_f(unsigned v) { return __uint_as_float(v & 0xffff0000u); }
__device__ __forceinline__ float lrelu(float v) { return fmaxf(v, 0.2f * v); }
__device__ __forceinline__ float elu(float v) { return v > 0.f ? v : __expf(v) - 1.f; }

struct P8 { const void* src[8]; int dstoff[8]; int n[8]; };

struct MegaArgs {
  const void* x; const int* eidx; const int* etype;
  const void* w0; const void* w1; const void* pW0; const void* pW1;
  P8 tab; float* base;
  int* flags; unsigned short* xw; float4* qi4; float4* kj4; unsigned short* aggb;
  int* dstA; int* pk; int* eord; int* deg; int* cnt; int* bcnt;
  int* excl; int* rowstart; int* bsum; int* nq; int* nw;
  unsigned short* Wbt; unsigned short* pWTb2; unsigned short* qkt_hi; unsigned short* qkt_lo;
  float* Qf; float* Kf; float* cbf; float* pbf; float* bo2;
  void* dout;
};

// ====== phase bodies (verified on-device via R8 mega run) ======

__device__ __forceinline__ void phase_zero(const MegaArgs& a, int vb, int t) {
  int i = vb * 256 + t;
  if (i < 2 * NPAD + 16) a.deg[i] = 0;        // deg|cnt|bcnt contiguous
}

__device__ __forceinline__ void phase_detect(const MegaArgs& a, int t, int* dcnt) {
  if (t < 2) dcnt[t] = 0;
  __syncthreads();
  unsigned short v = ((const unsigned short*)a.x)[2 * t];
  int ex = (v >> 7) & 0xFF;
  if (ex < 119 || ex > 135) atomicAdd(&dcnt[0], 1);
  if (a.eidx[2 * t + 1] != 0) atomicAdd(&dcnt[1], 1);
  __syncthreads();
  if (t == 0) {
    a.flags[0] = (dcnt[0] > 64) ? 1 : 0;
    a.flags[1] = (dcnt[1] == 0) ? 1 : 0;
  }
}

__device__ __forceinline__ void phase_cvt(const MegaArgs& a, int vb, int t) {
  const int f0 = a.flags[0], f1 = a.flags[1];
  if (vb < VB_IDX) {
    int e = vb * 256 + t;
    if (e < E_EDGES) {
      int s, d, r;
      if (f1) {
        const long long* e64 = (const long long*)a.eidx;
        const long long* t64 = (const long long*)a.etype;
        s = (int)e64[e]; d = (int)e64[E_EDGES + e]; r = (int)t64[e];
      } else {
        s = a.eidx[e]; d = a.eidx[E_EDGES + e]; r = a.etype[e];
      }
      a.dstA[e] = d;
      a.pk[e] = s | (r << 16);
      atomicAdd(&a.deg[d], 1);
    }
  } else if (vb < VB_IDX + VB_WT) {
    int idx = (vb - VB_IDX) * 256 + t;
    int l = idx >> 15, rem = idx & 32767;
    int r = rem >> 14, i = (rem >> 7) & 127, o = rem & 127;
    const void* src = l ? a.w1 : a.w0;
    unsigned short v;
    if (f0) v = f2bf_bits(((const float*)src)[rem]);
    else    v = ((const unsigned short*)src)[rem];
    a.Wbt[(size_t)l * 2 * HID * HID + ((size_t)r * HID + o) * HID + i] = v;
  } else {
    int bb = vb - VB_IDX - VB_WT;             // 0..1
    for (int k = 0; k < 8; ++k) {
      int n = a.tab.n[k];
      for (int i = bb * 256 + t; i < n; i += 2 * 256) {
        float v = f0 ? ((const float*)a.tab.src[k])[i] : bf2f(((const unsigned short*)a.tab.src[k])[i]);
        a.base[a.tab.dstoff[k] + i] = v;
      }
    }
  }
}

__device__ __forceinline__ void phase_scan1(const MegaArgs& a, int vb, int t, int* sm) {
  int i = vb * 256 + t;
  int v = (i < NPAD) ? a.deg[i] : 0;
  sm[t] = v;
  __syncthreads();
#pragma unroll
  for (int off = 1; off < 256; off <<= 1) {
    int add = (t >= off) ? sm[t - off] : 0;
    __syncthreads();
    sm[t] += add;
    __syncthreads();
  }
  if (i < NPAD) a.excl[i] = sm[t] - v;
  if (t == 255) a.bsum[vb] = sm[255];
}

__device__ __forceinline__ void phase_bucket(const MegaArgs& a, int vb, int t, int lane) {
  int n = vb * 256 + t;
  bool valid = n < N_NODES;
  int d = valid ? a.deg[n] : 0;
  bool isq = valid && (d <= 16);
  bool isw = valid && (d > 16);
  unsigned long long mq = __ballot(isq);
  unsigned long long mw = __ballot(isw);
  unsigned long long lower = (lane == 63) ? 0x7fffffffffffffffull : ((1ull << lane) - 1ull);
  int baseq = 0, basew = 0;
  int lq = (int)__ffsll(mq) - 1;
  int lw = (int)__ffsll(mw) - 1;
  if (mq && lane == lq) baseq = atomicAdd(&a.bcnt[0], (int)__popcll(mq));
  if (mw && lane == lw) basew = atomicAdd(&a.bcnt[1], (int)__popcll(mw));
  if (mq) baseq = __shfl(baseq, lq);
  if (mw) basew = __shfl(basew, lw);
  if (isq) a.nq[baseq + (int)__popcll(mq & lower)] = n;
  if (isw) a.nw[basew + (int)__popcll(mw & lower)] = n;
}

__device__ __forceinline__ void phase_wq(const MegaArgs& a, int vb, int t) {
  int idx = vb * 256 + t;                     // (l,r,i)
  int i = idx & 127, lr = idx >> 7, l = lr >> 1, r = (lr & 1);
  float aq[4] = {0.f, 0.f, 0.f, 0.f}, ak[4] = {0.f, 0.f, 0.f, 0.f};
  const unsigned short* Wb = a.Wbt + (size_t)lr * HID * HID;
  const float* Qp = a.Qf + l * HID * HEADS;
  const float* Kp = a.Kf + l * HID * HEADS;
  for (int j = 0; j < HID; ++j) {
    float w = bf2f(Wb[j * HID + i]);
    float4 q4 = *(const float4*)(Qp + j * 4);
    float4 k4 = *(const float4*)(Kp + j * 4);
    aq[0] += w * q4.x; aq[1] += w * q4.y; aq[2] += w * q4.z; aq[3] += w * q4.w;
    ak[0] += w * k4.x; ak[1] += w * k4.y; ak[2] += w * k4.z; ak[3] += w * k4.w;
  }
  size_t base = (size_t)l * 16 * HID;
#pragma unroll
  for (int h = 0; h < 4; ++h) {
    unsigned short qh = f2bf_bits(aq[h]);
    unsigned short kh = f2bf_bits(ak[h]);
    float qres = aq[h] - bf2f(qh);
    float kres = ak[h] - bf2f(kh);
    a.qkt_hi[base + (size_t)(r * 4 + h) * HID + i] = qh;
    a.qkt_lo[base + (size_t)(r * 4 + h) * HID + i] = f2bf_bits(qres);
    a.qkt_hi[base + (size_t)(8 + r * 4 + h) * HID + i] = kh;
    a.qkt_lo[base + (size_t)(8 + r * 4 + h) * HID + i] = f2bf_bits(kres);
  }
}

__device__ __forceinline__ void phase_pproj(const MegaArgs& a, int vb, int wave, int lane) {
  const int f0 = a.flags[0];
  int ob = vb * 4 + wave;                     // 0..255
  int o = ob & 127, l = ob >> 7;
  const void* pWraw = l ? a.pW1 : a.pW0;
  const float* cb = a.cbf + l * HID;
  float part = 0.f;
#pragma unroll
  for (int i = lane; i < HID; i += 64) {
    float w = f0 ? ((const float*)pWraw)[o * HID + i] : bf2f(((const unsigned short*)pWraw)[o * HID + i]);
    a.pWTb2[(size_t)l * HID * HID + o * HID + i] = f2bf_bits(w);
    part += cb[i] * w;
  }
#pragma unroll
  for (int off = 32; off > 0; off >>= 1) part += __shfl_xor(part, off);
  if (lane == 0) a.bo2[l * HID + o] = a.pbf[l * HID + o] + part;
}

__device__ __forceinline__ void phase_scan23(const MegaArgs& a, int vb, int t, int* sm) {
  int v = (t < SCAN_B) ? a.bsum[t] : 0;
  sm[t] = v;
  __syncthreads();
#pragma unroll
  for (int off = 1; off < 256; off <<= 1) {
    int add = (t >= off) ? sm[t - off] : 0;
    __syncthreads();
    sm[t] += add;
    __syncthreads();
  }
  int bpre = (vb > 0) ? sm[vb - 1] : 0;
  int i = vb * 256 + t;
  if (i < NPAD) a.rowstart[i] = a.excl[i] + bpre;
  if (i == 0) a.rowstart[NPAD] = E_EDGES;
}

__device__ __forceinline__ void phase_scatter(const MegaArgs& a, int vb, int t) {
  int e = vb * 256 + t;
  if (e < E_EDGES) {
    int d = a.dstA[e];
    int pos = a.rowstart[d] + atomicAdd(&a.cnt[d], 1);
    a.eord[pos] = a.pk[e];
  }
}

// gemm body: As (64 rows bf16 in LDS) @ Wbt[r] -> xw, restaged through Cs.
__device__ __forceinline__ void gemm64_from_lds(unsigned short (*As)[136], unsigned short (*Cs)[136],
                                                const unsigned short* __restrict__ Wbt,
                                                unsigned short* __restrict__ xw, int row0,
                                                int wave, int lm, int q, int t) {
  const int r = wave >> 1, colb = (wave & 1) * 64;
  const unsigned short* Bt = Wbt + (size_t)r * HID * HID;
  s16x8 bfr[4][4];
#pragma unroll
  for (int kc = 0; kc < 4; ++kc) {
    const int ko = kc * 32 + q * 8;
#pragma unroll
    for (int ct = 0; ct < 4; ++ct)
      bfr[kc][ct] = *(const s16x8*)(Bt + (size_t)(colb + ct * 16 + lm) * HID + ko);
  }
  f32x4 acc[4][4];
#pragma unroll
  for (int aa = 0; aa < 4; ++aa)
#pragma unroll
    for (int c = 0; c < 4; ++c) { f32x4 z = {0.f, 0.f, 0.f, 0.f}; acc[aa][c] = z; }
#pragma unroll
  for (int kc = 0; kc < 4; ++kc) {
    const int ko = kc * 32 + q * 8;
#pragma unroll
    for (int rt = 0; rt < 4; ++rt) {
      s16x8 av = *(const s16x8*)&As[rt * 16 + lm][ko];
#pragma unroll
      for (int ct = 0; ct < 4; ++ct)
        acc[rt][ct] = __builtin_amdgcn_mfma_f32_16x16x32_bf16(av, bfr[kc][ct], acc[rt][ct], 0, 0, 0);
    }
  }
  __syncthreads();
#pragma unroll
  for (int rr = 0; rr < 2; ++rr) {
    if (r == rr) {
#pragma unroll
      for (int rt = 0; rt < 4; ++rt)
#pragma unroll
        for (int i = 0; i < 4; ++i) {
          int rloc = rt * 16 + q * 4 + i;
#pragma unroll
          for (int ct = 0; ct < 4; ++ct)
            Cs[rloc][colb + ct * 16 + lm] = f2bf_bits(acc[rt][ct][i]);
        }
    }
    __syncthreads();
    unsigned short* dst = xw + ((size_t)rr * NPAD + row0) * HID;
#pragma unroll
    for (int j = 0; j < 4; ++j) {
      int idx = j * 256 + t;                  // 1024 16B units
      int rw = idx >> 4, cb8 = (idx & 15) * 8;
      if (row0 + rw < N_NODES)
        *(s16x8*)(dst + (size_t)rw * HID + cb8) = *(const s16x8*)&Cs[rw][cb8];
    }
    __syncthreads();
  }
}

// qk body: wave w handles rows [16w,16w+16) of As; writes qi4/kj4.
__device__ __forceinline__ void qk16_from_lds(unsigned short (*As)[136], unsigned short (*Cs)[136],
                                              const unsigned short* __restrict__ qkt_hi,
                                              const unsigned short* __restrict__ qkt_lo,
                                              float4* __restrict__ qi4, float4* __restrict__ kj4,
                                              int row0, int wave, int lane, int lm, int q) {
  s16x8 bhi[4], blo[4], af[4];
#pragma unroll
  for (int kc = 0; kc < 4; ++kc) {
    const int ko = kc * 32 + q * 8;
    bhi[kc] = *(const s16x8*)(qkt_hi + (size_t)lm * HID + ko);
    blo[kc] = *(const s16x8*)(qkt_lo + (size_t)lm * HID + ko);
    af[kc]  = *(const s16x8*)&As[wave * 16 + lm][ko];
  }
  f32x4 acc = {0.f, 0.f, 0.f, 0.f};
#pragma unroll
  for (int kc = 0; kc < 4; ++kc) {
    acc = __builtin_amdgcn_mfma_f32_16x16x32_bf16(af[kc], bhi[kc], acc, 0, 0, 0);
    acc = __builtin_amdgcn_mfma_f32_16x16x32_bf16(af[kc], blo[kc], acc, 0, 0, 0);
  }
  float (*Fs)[16][17] = (float(*)[16][17])&Cs[0][0];   // 4*16*17*4 = 17408 B
#pragma unroll
  for (int i = 0; i < 4; ++i)
    Fs[wave][lm][q * 4 + i] = acc[i];
  __syncthreads();
  if (lane < 16) {
    int n = row0 + wave * 16 + lane;
    if (n < N_NODES) {
      float4 v;
      v.x = Fs[wave][0][lane];  v.y = Fs[wave][1][lane];  v.z = Fs[wave][2][lane];  v.w = Fs[wave][3][lane];
      qi4[n] = v;
      v.x = Fs[wave][4][lane];  v.y = Fs[wave][5][lane];  v.z = Fs[wave][6][lane];  v.w = Fs[wave][7][lane];
      qi4[NPAD + n] = v;
      v.x = Fs[wave][8][lane];  v.y = Fs[wave][9][lane];  v.z = Fs[wave][10][lane]; v.w = Fs[wave][11][lane];
      kj4[n] = v;
      v.x = Fs[wave][12][lane]; v.y = Fs[wave][13][lane]; v.z = Fs[wave][14][lane]; v.w = Fs[wave][15][lane];
      kj4[NPAD + n] = v;
    }
  }
  __syncthreads();
}

__device__ __forceinline__ void phase_l0(const MegaArgs& a, int vb, int t, int wave, int lane, int lm, int q,
                                         unsigned short (*As)[136], unsigned short (*Cs)[136]) {
  const int row0 = vb * 64;
  if (a.flags[0]) {
    const float* xf = (const float*)a.x;
#pragma unroll
    for (int j = 0; j < 4; ++j) {
      int idx = j * 256 + t;
      int rw = idx >> 4, cb8 = (idx & 15) * 8;
      s16x8 o = {0, 0, 0, 0, 0, 0, 0, 0};
      if (row0 + rw < N_NODES) {
        const float4* s4 = (const float4*)(xf + (size_t)(row0 + rw) * HID + cb8);
        float4 aa = s4[0], b = s4[1];
        o[0] = (short)f2bf_bits(aa.x); o[1] = (short)f2bf_bits(aa.y);
        o[2] = (short)f2bf_bits(aa.z); o[3] = (short)f2bf_bits(aa.w);
        o[4] = (short)f2bf_bits(b.x);  o[5] = (short)f2bf_bits(b.y);
        o[6] = (short)f2bf_bits(b.z);  o[7] = (short)f2bf_bits(b.w);
      }
      *(s16x8*)&As[rw][cb8] = o;
    }
  } else {
    const unsigned short* xb = (const unsigned short*)a.x;
#pragma unroll
    for (int j = 0; j < 4; ++j) {
      int idx = j * 256 + t;
      int rw = idx >> 4, cb8 = (idx & 15) * 8;
      s16x8 o = {0, 0, 0, 0, 0, 0, 0, 0};
      if (row0 + rw < N_NODES)
        o = *(const s16x8*)(xb + (size_t)(row0 + rw) * HID + cb8);
      *(s16x8*)&As[rw][cb8] = o;
    }
  }
  __syncthreads();
  gemm64_from_lds(As, Cs, a.Wbt, a.xw, row0, wave, lm, q, t);
  qk16_from_lds(As, Cs, a.qkt_hi, a.qkt_lo, a.qi4, a.kj4, row0, wave, lane, lm, q);
}

__device__ __forceinline__ void phase_mid(const MegaArgs& a, int vb, int t, int wave, int lane, int lm, int q,
                                          unsigned short (*As)[136], unsigned short (*Cs)[136]) {
  const int row0 = vb * 64;
  const int h = wave >> 1;
  const int colb = (wave & 1) * 64;
  s16x8 bfr[4][4];
#pragma unroll
  for (int kc = 0; kc < 4; ++kc) {
    const int ko = kc * 32 + q * 8;
#pragma unroll
    for (int ct = 0; ct < 4; ++ct)
      bfr[kc][ct] = *(const s16x8*)(a.pWTb2 + (size_t)(colb + ct * 16 + lm) * HID + ko);
  }
  const unsigned short* gsrc = a.aggb + (size_t)row0 * HID;
#pragma unroll
  for (int j = 0; j < 4; ++j) {
    int idx = j * 256 + t;
    *(s16x8*)&As[idx >> 4][(idx & 15) * 8] = *(const s16x8*)(gsrc + idx * 8);
  }
  __syncthreads();
  f32x4 pacc[2][4];
#pragma unroll
  for (int aa = 0; aa < 2; ++aa)
#pragma unroll
    for (int c = 0; c < 4; ++c) { f32x4 z = {0.f, 0.f, 0.f, 0.f}; pacc[aa][c] = z; }
#pragma unroll
  for (int kc = 0; kc < 4; ++kc) {
    const int ko = kc * 32 + q * 8;
#pragma unroll
    for (int rt = 0; rt < 2; ++rt) {
      s16x8 av = *(const s16x8*)&As[(2 * h + rt) * 16 + lm][ko];
#pragma unroll
      for (int ct = 0; ct < 4; ++ct)
        pacc[rt][ct] = __builtin_amdgcn_mfma_f32_16x16x32_bf16(av, bfr[kc][ct], pacc[rt][ct], 0, 0, 0);
    }
  }
  __syncthreads();
#pragma unroll
  for (int rt = 0; rt < 2; ++rt)
#pragma unroll
    for (int i = 0; i < 4; ++i) {
      int rloc = (2 * h + rt) * 16 + q * 4 + i;
#pragma unroll
      for (int ct = 0; ct < 4; ++ct) {
        int o = colb + ct * 16 + lm;
        As[rloc][o] = f2bf_bits(elu(pacc[rt][ct][i] + a.bo2[o]));
      }
    }
  __syncthreads();
  const unsigned short* Wbt1 = a.Wbt + (size_t)2 * HID * HID;
  gemm64_from_lds(As, Cs, Wbt1, a.xw, row0, wave, lm, q, t);
  qk16_from_lds(As, Cs, a.qkt_hi + (size_t)16 * HID, a.qkt_lo + (size_t)16 * HID,
                a.qi4, a.kj4, row0, wave, lane, lm, q);
}

__device__ __forceinline__ void phase_final(const MegaArgs& a, int vb, int t, int wave, int lane, int lm, int q,
                                            unsigned short (*As)[136]) {
  const int row0 = vb * 64;
  const int h = wave >> 1;
  const int colb = (wave & 1) * 64;
  const unsigned short* pWT1 = a.pWTb2 + (size_t)HID * HID;
  const float* bo1 = a.bo2 + HID;
  s16x8 bfr[4][4];
#pragma unroll
  for (int kc = 0; kc < 4; ++kc) {
    const int ko = kc * 32 + q * 8;
#pragma unroll
    for (int ct = 0; ct < 4; ++ct)
      bfr[kc][ct] = *(const s16x8*)(pWT1 + (size_t)(colb + ct * 16 + lm) * HID + ko);
  }
  const unsigned short* gsrc = a.aggb + (size_t)row0 * HID;
#pragma unroll
  for (int j = 0; j < 4; ++j) {
    int idx = j * 256 + t;
    *(s16x8*)&As[idx >> 4][(idx & 15) * 8] = *(const s16x8*)(gsrc + idx * 8);
  }
  __syncthreads();
  f32x4 acc[2][4];
#pragma unroll
  for (int aa = 0; aa < 2; ++aa)
#pragma unroll
    for (int c = 0; c < 4; ++c) { f32x4 z = {0.f, 0.f, 0.f, 0.f}; acc[aa][c] = z; }
#pragma unroll
  for (int kc = 0; kc < 4; ++kc) {
    const int ko = kc * 32 + q * 8;
#pragma unroll
    for (int rt = 0; rt < 2; ++rt) {
      s16x8 av = *(const s16x8*)&As[(2 * h + rt) * 16 + lm][ko];
#pragma unroll
      for (int ct = 0; ct < 4; ++ct)
        acc[rt][ct] = __builtin_amdgcn_mfma_f32_16x16x32_bf16(av, bfr[kc][ct], acc[rt][ct], 0, 0, 0);
    }
  }
  __syncthreads();
  if (!a.flags[0]) {
    unsigned short* dstp = (unsigned short*)a.dout;
#pragma unroll
    for (int rt = 0; rt < 2; ++rt)
#pragma unroll
      for (int i = 0; i < 4; ++i) {
        int rloc = (2 * h + rt) * 16 + q * 4 + i;
#pragma unroll
        for (int ct = 0; ct < 4; ++ct) {
          int o = colb + ct * 16 + lm;
          As[rloc][o] = f2bf_bits(elu(acc[rt][ct][i] + bo1[o]));
        }
      }
    __syncthreads();
#pragma unroll
    for (int j = 0; j < 4; ++j) {
      int idx = j * 256 + t;
      int rw = idx >> 4, cb8 = (idx & 15) * 8;
      if (row0 + rw < N_NODES)
        *(s16x8*)(dstp + (size_t)(row0 + rw) * HID + cb8) = *(const s16x8*)&As[rw][cb8];
    }
    __syncthreads();
  } else {
    float* fdst = (float*)a.dout;
    float (*Fs)[132] = (float(*)[132])&As[0][0];   // 32*132*4 = 16896 B
#pragma unroll
    for (int h2 = 0; h2 < 2; ++h2) {
      if (h == h2) {
#pragma unroll
        for (int rt = 0; rt < 2; ++rt)
#pragma unroll
          for (int i = 0; i < 4; ++i) {
            int rloc = rt * 16 + q * 4 + i;
#pragma unroll
            for (int ct = 0; ct < 4; ++ct) {
              int o = colb + ct * 16 + lm;
              Fs[rloc][o] = elu(acc[rt][ct][i] + bo1[o]);
            }
          }
      }
      __syncthreads();
#pragma unroll
      for (int j = 0; j < 4; ++j) {
        int idx = j * 256 + t;
        int rw = idx >> 5, cb4 = (idx & 31) * 4;
        if (row0 + h2 * 32 + rw < N_NODES)
          *(float4*)(fdst + (size_t)(row0 + h2 * 32 + rw) * HID + cb4) = *(const float4*)&Fs[rw][cb4];
      }
      __syncthreads();
    }
  }
}

// edge body for one block (big-first ordering)
__device__ __forceinline__ void edge_vb(const MegaArgs& a, int vb, volatile float* wbuf,
                                        int wave, int lane) {
  const float4* qi4 = a.qi4;
  const float4* kj4 = a.kj4;
  const unsigned short* xw = a.xw;
  if (vb >= VB_BIG) {
    // ---- quad: 4 nodes/wave, 16 lanes/node, 8 ch/lane ----
    const int g = lane >> 4, li = lane & 15;
    const int idx = (vb - VB_BIG) * 16 + wave * 4 + g;
    const int cq = a.bcnt[0];
    const bool act = idx < cq;
    const int n = act ? a.nq[idx] : 0;
    const int start = a.rowstart[n];
    const int dg = act ? (a.rowstart[n + 1] - start) : 0;
    int p = 0;
    float w0 = 0.f, w1 = 0.f, w2 = 0.f, w3 = 0.f;
    if (li < dg) {
      p = a.eord[start + li];
      int s = p & 0xffff, r = p >> 16;
      float4 k4 = kj4[r ? (NPAD + s) : s];
      float4 q4 = r ? qi4[NPAD + n] : qi4[n];
      w0 = __expf(fminf(lrelu(q4.x + k4.x), 85.f));
      w1 = __expf(fminf(lrelu(q4.y + k4.y), 85.f));
      w2 = __expf(fminf(lrelu(q4.z + k4.z), 85.f));
      w3 = __expf(fminf(lrelu(q4.w + k4.w), 85.f));
    }
    const int wg = (wave << 2) | g;
    volatile float* wls = &wbuf[wg * 68];     // [4][17]
    wls[0 * 17 + li] = w0; wls[1 * 17 + li] = w1;
    wls[2 * 17 + li] = w2; wls[3 * 17 + li] = w3;
    float s0 = w0, s1 = w1, s2 = w2, s3 = w3;
#pragma unroll
    for (int off = 8; off > 0; off >>= 1) {
      s0 += __shfl_xor(s0, off); s1 += __shfl_xor(s1, off);
      s2 += __shfl_xor(s2, off); s3 += __shfl_xor(s3, off);
    }
    const int hh = li >> 2;
    float ssel = hh == 0 ? s0 : hh == 1 ? s1 : hh == 2 ? s2 : s3;
    float a0 = 0.f, a1 = 0.f, a2 = 0.f, a3 = 0.f, a4 = 0.f, a5 = 0.f, a6 = 0.f, a7 = 0.f;
    volatile const float* wrh = &wls[hh * 17];
    const int co = li * 8;
    const int gbase = lane & 48;
#pragma unroll 1
    for (int e0 = 0; e0 < dg; e0 += 4) {
      int pe[4];
      uint4 v[4];
#pragma unroll
      for (int u = 0; u < 4; ++u) {
        int e = e0 + u;
        pe[u] = __shfl(p, gbase + (e < dg ? e : 0));
      }
#pragma unroll
      for (int u = 0; u < 4; ++u)
        v[u] = *(const uint4*)(xw + ((size_t)((pe[u] & 0xffff) + (pe[u] >> 16) * NPAD) << 7) + co);
#pragma unroll
      for (int u = 0; u < 4; ++u) {
        int e = e0 + u;
        float we = (e < dg) ? wrh[e] : 0.f;
        a0 = fmaf(lo_f(v[u].x), we, a0); a1 = fmaf(hi_f(v[u].x), we, a1);
        a2 = fmaf(lo_f(v[u].y), we, a2); a3 = fmaf(hi_f(v[u].y), we, a3);
        a4 = fmaf(lo_f(v[u].z), we, a4); a5 = fmaf(hi_f(v[u].z), we, a5);
        a6 = fmaf(lo_f(v[u].w), we, a6); a7 = fmaf(hi_f(v[u].w), we, a7);
      }
    }
    if (act) {
      float inv = 1.f / (ssel + 1e-16f);
      uint4 o;
      o.x = (unsigned)f2bf_bits(a0 * inv) | ((unsigned)f2bf_bits(a1 * inv) << 16);
      o.y = (unsigned)f2bf_bits(a2 * inv) | ((unsigned)f2bf_bits(a3 * inv) << 16);
      o.z = (unsigned)f2bf_bits(a4 * inv) | ((unsigned)f2bf_bits(a5 * inv) << 16);
      o.w = (unsigned)f2bf_bits(a6 * inv) | ((unsigned)f2bf_bits(a7 * inv) << 16);
      *(uint4*)(a.aggb + ((size_t)n << 7) + co) = o;
    }
  } else {
    // ---- big: one wave per node ----
    const int idx = vb * 4 + wave;
    const int cw = a.bcnt[1];
    if (idx < cw) {
      const int n = a.nw[idx];
      unsigned* outp = (unsigned*)(a.aggb + ((size_t)n << 7)) + lane;
      const int start = a.rowstart[n];
      const int deg = a.rowstart[n + 1] - start;
      const int hh = lane >> 4;
      const int ch2 = lane << 1;
      float2 acc = {0.f, 0.f};
      float ssel;
      volatile float* wls = &wbuf[wave * 288];  // [4][72]
      if (deg <= 64) {
        int p = 0;
        float w0 = 0.f, w1 = 0.f, w2 = 0.f, w3 = 0.f;
        if (lane < deg) {
          p = a.eord[start + lane];
          int s = p & 0xffff, r = p >> 16;
          float4 k4 = kj4[r ? (NPAD + s) : s];
          float4 q4 = r ? qi4[NPAD + n] : qi4[n];
          w0 = __expf(fminf(lrelu(q4.x + k4.x), 85.f));
          w1 = __expf(fminf(lrelu(q4.y + k4.y), 85.f));
          w2 = __expf(fminf(lrelu(q4.z + k4.z), 85.f));
          w3 = __expf(fminf(lrelu(q4.w + k4.w), 85.f));
        }
        float s0 = w0, s1 = w1, s2 = w2, s3 = w3;
#pragma unroll
        for (int off = 32; off > 0; off >>= 1) {
          s0 += __shfl_xor(s0, off); s1 += __shfl_xor(s1, off);
          s2 += __shfl_xor(s2, off); s3 += __shfl_xor(s3, off);
        }
        ssel = hh == 0 ? s0 : hh == 1 ? s1 : hh == 2 ? s2 : s3;
        wls[0 * 72 + lane] = w0;
        wls[1 * 72 + lane] = w1;
        wls[2 * 72 + lane] = w2;
        wls[3 * 72 + lane] = w3;
        volatile const float* wrh = &wls[hh * 72];
        const int degp = (deg + 15) & ~15;
#pragma unroll 1
        for (int e = 0; e < degp; e += 16) {
          int pp[16];
          unsigned vv[16];
#pragma unroll
          for (int u = 0; u < 16; ++u)
            pp[u] = __builtin_amdgcn_readlane(p, e + u);
#pragma unroll
          for (int u = 0; u < 16; ++u)
            vv[u] = *(const unsigned*)(xw + ((size_t)((pp[u] & 0xffff) + (pp[u] >> 16) * NPAD) << 7) + ch2);
#pragma unroll
          for (int u = 0; u < 16; ++u) {
            float we = wrh[e + u];
            acc.x = fmaf(lo_f(vv[u]), we, acc.x);
            acc.y = fmaf(hi_f(vv[u]), we, acc.y);
          }
        }
      } else {
        const float4 q0 = qi4[n], q1 = qi4[NPAD + n];
        float4 m = make_float4(-1e30f, -1e30f, -1e30f, -1e30f);
        for (int e = start; e < start + deg; ++e) {
          int pe = a.eord[e];
          int s = pe & 0xffff, r = pe >> 16;
          float4 k4 = kj4[(size_t)r * NPAD + s];
          float4 q4 = r ? q1 : q0;
          m.x = fmaxf(m.x, lrelu(q4.x + k4.x)); m.y = fmaxf(m.y, lrelu(q4.y + k4.y));
          m.z = fmaxf(m.z, lrelu(q4.z + k4.z)); m.w = fmaxf(m.w, lrelu(q4.w + k4.w));
        }
        float4 sv = make_float4(0.f, 0.f, 0.f, 0.f);
        for (int e = start; e < start + deg; ++e) {
          int pe = a.eord[e];
          int s = pe & 0xffff, r = pe >> 16;
          float4 k4 = kj4[(size_t)r * NPAD + s];
          float4 q4 = r ? q1 : q0;
          float w0 = __expf(lrelu(q4.x + k4.x) - m.x);
          float w1 = __expf(lrelu(q4.y + k4.y) - m.y);
          float w2 = __expf(lrelu(q4.z + k4.z) - m.z);
          float w3 = __expf(lrelu(q4.w + k4.w) - m.w);
          sv.x += w0; sv.y += w1; sv.z += w2; sv.w += w3;
          float we = hh == 0 ? w0 : hh == 1 ? w1 : hh == 2 ? w2 : w3;
          unsigned v = *(const unsigned*)(xw + (((size_t)r * NPAD + s) << 7) + ch2);
          acc.x = fmaf(lo_f(v), we, acc.x);
          acc.y = fmaf(hi_f(v), we, acc.y);
        }
        ssel = hh == 0 ? sv.x : hh == 1 ? sv.y : hh == 2 ? sv.z : sv.w;
      }
      float inv = 1.f / (ssel + 1e-16f);
      *outp = (unsigned)f2bf_bits(acc.x * inv) | ((unsigned)f2bf_bits(acc.y * inv) << 16);
    }
  }
}

// ====== dispatch kernels ======
__global__ __launch_bounds__(256) void k_zero(MegaArgs a) {
  __shared__ int dcnt[2];
  phase_zero(a, blockIdx.x, threadIdx.x);
  if (blockIdx.x == 0) phase_detect(a, threadIdx.x, dcnt);
}
__global__ __launch_bounds__(256) void k_cvt(MegaArgs a) {
  phase_cvt(a, blockIdx.x, threadIdx.x);
}
// scan1 | bucket | prep_wq | prep_proj fused by block range
__global__ __launch_bounds__(256) void k_s1prep(MegaArgs a) {
  __shared__ int sm[256];
  const int b = blockIdx.x, t = threadIdx.x;
  if (b < SCAN_B)                phase_scan1(a, b, t, sm);
  else if (b < 2 * SCAN_B)       phase_bucket(a, b - SCAN_B, t, t & 63);
  else if (b < 2 * SCAN_B + 2)   phase_wq(a, b - 2 * SCAN_B, t);
  else                           phase_pproj(a, b - 2 * SCAN_B - 2, t >> 6, t & 63);
}
__global__ __launch_bounds__(256) void k_scan23(MegaArgs a) {
  __shared__ int sm[256];
  phase_scan23(a, blockIdx.x, threadIdx.x, sm);
}
// l0 (blocks [0,VB_ROWS)) || scatter (blocks [VB_ROWS, +VB_SCAT)) — independent chains
__global__ __launch_bounds__(256) void k_scat_l0(MegaArgs a) {
  __shared__ unsigned short As[64][136];
  __shared__ unsigned short Cs[64][136];
  const int b = blockIdx.x, t = threadIdx.x;
  if (b < VB_ROWS) {
    const int wave = t >> 6, lane = t & 63;
    phase_l0(a, b, t, wave, lane, lane & 15, lane >> 4, As, Cs);
  } else {
    phase_scatter(a, b - VB_ROWS, t);
  }
}
__global__ __launch_bounds__(256) void k_edge(MegaArgs a) {
  __shared__ volatile float wbuf[1152];
  edge_vb(a, blockIdx.x, wbuf, threadIdx.x >> 6, threadIdx.x & 63);
}
__global__ __launch_bounds__(256) void k_mid(MegaArgs a) {
  __shared__ unsigned short As[64][136];
  __shared__ unsigned short Cs[64][136];
  const int t = threadIdx.x, wave = t >> 6, lane = t & 63;
  phase_mid(a, blockIdx.x, t, wave, lane, lane & 15, lane >> 4, As, Cs);
}
__global__ __launch_bounds__(256) void k_final(MegaArgs a) {
  __shared__ unsigned short As[64][136];
  const int t = threadIdx.x, wave = t >> 6, lane = t & 63;
  phase_final(a, blockIdx.x, t, wave, lane, lane & 15, lane >> 4, As);
}

extern "C" void kernel_launch(void* const* d_in, const int* in_sizes, int n_in,
                              void* d_out, int out_size, void* d_ws, size_t ws_size,
                              hipStream_t stream) {
  const int iW[2] = {3, 9}, iQ[2] = {4, 10}, iK[2] = {5, 11}, icb[2] = {6, 12}, ipW[2] = {7, 13}, ipb[2] = {8, 14};

  float* ws = (float*)d_ws;
  size_t off = 0;
  int*   flags = (int*)(ws + off); off += 16;
  unsigned short* xw   = (unsigned short*)(ws + off); off += (size_t)NPAD * HID;       // [2][NPAD][128] bf16
  float* qi   = ws + off; off += (size_t)2 * NPAD * HEADS;
  float* kj   = ws + off; off += (size_t)2 * NPAD * HEADS;
  unsigned short* aggb = (unsigned short*)(ws + off); off += (size_t)NPAD * HID / 2;
  int* dstA = (int*)(ws + off); off += E_EDGES;
  int* pk   = (int*)(ws + off); off += E_EDGES;
  int* eord = (int*)(ws + off); off += E_EDGES;
  int* deg  = (int*)(ws + off); off += NPAD;        // deg|cnt|bcnt contiguous for one zero pass
  int* cnt  = (int*)(ws + off); off += NPAD;
  int* bcnt = (int*)(ws + off); off += 16;
  int* excl = (int*)(ws + off); off += NPAD;
  int* rowstart = (int*)(ws + off); off += NPAD + 16;
  int* bsum  = (int*)(ws + off); off += 256;
  int* nq   = (int*)(ws + off); off += NPAD;
  int* nwl  = (int*)(ws + off); off += NPAD;
  unsigned short* Wbt   = (unsigned short*)(ws + off); off += (size_t)2 * 2 * HID * HID / 2;
  unsigned short* pWTb2 = (unsigned short*)(ws + off); off += (size_t)2 * HID * HID / 2;
  unsigned short* qkt_hi = (unsigned short*)(ws + off); off += (size_t)2 * 16 * HID / 2;
  unsigned short* qkt_lo = (unsigned short*)(ws + off); off += (size_t)2 * 16 * HID / 2;
  float* Qf  = ws + off; off += 2 * HID * HEADS;
  float* Kf  = ws + off; off += 2 * HID * HEADS;
  float* cbf = ws + off; off += 2 * HID;
  float* pbf = ws + off; off += 2 * HID;
  float* bo2 = ws + off; off += 2 * HID;

  MegaArgs a;
  a.x = d_in[0]; a.eidx = (const int*)d_in[1]; a.etype = (const int*)d_in[2];
  a.w0 = d_in[iW[0]]; a.w1 = d_in[iW[1]]; a.pW0 = d_in[ipW[0]]; a.pW1 = d_in[ipW[1]];
  for (int l = 0; l < 2; ++l) {
    a.tab.src[l * 4 + 0] = d_in[iQ[l]];  a.tab.dstoff[l * 4 + 0] = (int)(Qf - ws) + l * HID * HEADS;  a.tab.n[l * 4 + 0] = HID * HEADS;
    a.tab.src[l * 4 + 1] = d_in[iK[l]];  a.tab.dstoff[l * 4 + 1] = (int)(Kf - ws) + l * HID * HEADS;  a.tab.n[l * 4 + 1] = HID * HEADS;
    a.tab.src[l * 4 + 2] = d_in[icb[l]]; a.tab.dstoff[l * 4 + 2] = (int)(cbf - ws) + l * HID;         a.tab.n[l * 4 + 2] = HID;
    a.tab.src[l * 4 + 3] = d_in[ipb[l]]; a.tab.dstoff[l * 4 + 3] = (int)(pbf - ws) + l * HID;         a.tab.n[l * 4 + 3] = HID;
  }
  a.base = ws;
  a.flags = flags; a.xw = xw; a.qi4 = (float4*)qi; a.kj4 = (float4*)kj; a.aggb = aggb;
  a.dstA = dstA; a.pk = pk; a.eord = eord; a.deg = deg; a.cnt = cnt; a.bcnt = bcnt;
  a.excl = excl; a.rowstart = rowstart; a.bsum = bsum; a.nq = nq; a.nw = nwl;
  a.Wbt = Wbt; a.pWTb2 = pWTb2; a.qkt_hi = qkt_hi; a.qkt_lo = qkt_lo;
  a.Qf = Qf; a.Kf = Kf; a.cbf = cbf; a.pbf = pbf; a.bo2 = bo2;
  a.dout = d_out;

  // 9-dispatch chain; scatter overlapped with layer-0 compute (independent deps)
  k_zero<<<VB_ZERO, 256, 0, stream>>>(a);
  k_cvt<<<VB_CVT, 256, 0, stream>>>(a);
  k_s1prep<<<2 * SCAN_B + 2 + 64, 256, 0, stream>>>(a);
  k_scan23<<<SCAN_B, 256, 0, stream>>>(a);
  k_scat_l0<<<VB_ROWS + VB_SCAT, 256, 0, stream>>>(a);
  k_edge<<<VB_EDGE, 256, 0, stream>>>(a);
  k_mid<<<VB_ROWS, 256, 0, stream>>>(a);
  k_edge<<<VB_EDGE, 256, 0, stream>>>(a);
  k_final<<<VB_ROWS, 256, 0, stream>>>(a);
}

// Round 10
// 323.748 us; speedup vs baseline: 2.1841x; 1.0338x over previous
//
#include <hip/hip_runtime.h>
#include <hip/hip_bf16.h>

typedef __hip_bfloat16 bf16;
typedef short s16x8 __attribute__((ext_vector_type(8)));
typedef float f32x4 __attribute__((ext_vector_type(4)));

#define N_NODES 50000
#define NPAD    50048          // multiple of 64
#define E_EDGES 600000
#define HID     128
#define HEADS   4
#define SCAN_B  196            // ceil(NPAD/256)

// block counts
#define VB_ZERO 392            // ceil((2*NPAD+16)/256)
#define VB_IDX  2344           // ceil(E/256)
#define VB_WT   256
#define VB_CVT  (VB_IDX + VB_WT + 2)
#define VB_SCAT 2344
#define VB_ROWS 782            // NPAD/64
#define NBIG    1250           // big-node range: grid-strides over actual count
#define VB_QUAD 3125           // ceil(N/16)
#define VB_EDGE (NBIG + VB_QUAD)

// ---- float -> bf16 bits (RNE), finite inputs only ----
__device__ __forceinline__ unsigned short f2bf_bits(float f) {
  unsigned u = __float_as_uint(f);
  u += 0x7fffu + ((u >> 16) & 1u);
  return (unsigned short)(u >> 16);
}
__device__ __forceinline__ float bf2f(unsigned short b) {
  return __uint_as_float(((unsigned)b) << 16);
}
__device__ __forceinline__ float lo_f(unsigned v) { return __uint_as_float(v << 16); }
__device__ __forceinline__ float hi_f(unsigned v) { return __uint_as_float(v & 0xffff0000u); }
__device__ __forceinline__ float lrelu(float v) { return fmaxf(v, 0.2f * v); }
__device__ __forceinline__ float elu(float v) { return v > 0.f ? v : __expf(v) - 1.f; }

struct P8 { const void* src[8]; int dstoff[8]; int n[8]; };

struct MegaArgs {
  const void* x; const int* eidx; const int* etype;
  const void* w0; const void* w1; const void* pW0; const void* pW1;
  P8 tab; float* base;
  int* flags; unsigned short* xw; float4* qi4; float4* kj4; unsigned short* aggb;
  int* dstA; int* pk; int* eord; int* deg; int* cnt; int* bcnt;
  int* excl; int* rowstart; int* bsum; int* nq; int* nw;
  unsigned short* Wbt; unsigned short* pWTb2; unsigned short* qkt_hi; unsigned short* qkt_lo;
  float* Qf; float* Kf; float* cbf; float* pbf; float* bo2;
  void* dout;
};

// ====== phase bodies (verified on-device, R8/R9) ======

__device__ __forceinline__ void phase_zero(const MegaArgs& a, int vb, int t) {
  int i = vb * 256 + t;
  if (i < 2 * NPAD + 16) a.deg[i] = 0;        // deg|cnt|bcnt contiguous
}

__device__ __forceinline__ void phase_detect(const MegaArgs& a, int t, int* dcnt) {
  if (t < 2) dcnt[t] = 0;
  __syncthreads();
  unsigned short v = ((const unsigned short*)a.x)[2 * t];
  int ex = (v >> 7) & 0xFF;
  if (ex < 119 || ex > 135) atomicAdd(&dcnt[0], 1);
  if (a.eidx[2 * t + 1] != 0) atomicAdd(&dcnt[1], 1);
  __syncthreads();
  if (t == 0) {
    a.flags[0] = (dcnt[0] > 64) ? 1 : 0;
    a.flags[1] = (dcnt[1] == 0) ? 1 : 0;
  }
}

__device__ __forceinline__ void phase_cvt(const MegaArgs& a, int vb, int t) {
  const int f0 = a.flags[0], f1 = a.flags[1];
  if (vb < VB_IDX) {
    int e = vb * 256 + t;
    if (e < E_EDGES) {
      int s, d, r;
      if (f1) {
        const long long* e64 = (const long long*)a.eidx;
        const long long* t64 = (const long long*)a.etype;
        s = (int)e64[e]; d = (int)e64[E_EDGES + e]; r = (int)t64[e];
      } else {
        s = a.eidx[e]; d = a.eidx[E_EDGES + e]; r = a.etype[e];
      }
      a.dstA[e] = d;
      a.pk[e] = s | (r << 16);
      atomicAdd(&a.deg[d], 1);
    }
  } else if (vb < VB_IDX + VB_WT) {
    int idx = (vb - VB_IDX) * 256 + t;
    int l = idx >> 15, rem = idx & 32767;
    int r = rem >> 14, i = (rem >> 7) & 127, o = rem & 127;
    const void* src = l ? a.w1 : a.w0;
    unsigned short v;
    if (f0) v = f2bf_bits(((const float*)src)[rem]);
    else    v = ((const unsigned short*)src)[rem];
    a.Wbt[(size_t)l * 2 * HID * HID + ((size_t)r * HID + o) * HID + i] = v;
  } else {
    int bb = vb - VB_IDX - VB_WT;             // 0..1
    for (int k = 0; k < 8; ++k) {
      int n = a.tab.n[k];
      for (int i = bb * 256 + t; i < n; i += 2 * 256) {
        float v = f0 ? ((const float*)a.tab.src[k])[i] : bf2f(((const unsigned short*)a.tab.src[k])[i]);
        a.base[a.tab.dstoff[k] + i] = v;
      }
    }
  }
}

__device__ __forceinline__ void phase_scan1(const MegaArgs& a, int vb, int t, int* sm) {
  int i = vb * 256 + t;
  int v = (i < NPAD) ? a.deg[i] : 0;
  sm[t] = v;
  __syncthreads();
#pragma unroll
  for (int off = 1; off < 256; off <<= 1) {
    int add = (t >= off) ? sm[t - off] : 0;
    __syncthreads();
    sm[t] += add;
    __syncthreads();
  }
  if (i < NPAD) a.excl[i] = sm[t] - v;
  if (t == 255) a.bsum[vb] = sm[255];
}

__device__ __forceinline__ void phase_bucket(const MegaArgs& a, int vb, int t, int lane) {
  int n = vb * 256 + t;
  bool valid = n < N_NODES;
  int d = valid ? a.deg[n] : 0;
  bool isq = valid && (d <= 16);
  bool isw = valid && (d > 16);
  unsigned long long mq = __ballot(isq);
  unsigned long long mw = __ballot(isw);
  unsigned long long lower = (lane == 63) ? 0x7fffffffffffffffull : ((1ull << lane) - 1ull);
  int baseq = 0, basew = 0;
  int lq = (int)__ffsll(mq) - 1;
  int lw = (int)__ffsll(mw) - 1;
  if (mq && lane == lq) baseq = atomicAdd(&a.bcnt[0], (int)__popcll(mq));
  if (mw && lane == lw) basew = atomicAdd(&a.bcnt[1], (int)__popcll(mw));
  if (mq) baseq = __shfl(baseq, lq);
  if (mw) basew = __shfl(basew, lw);
  if (isq) a.nq[baseq + (int)__popcll(mq & lower)] = n;
  if (isw) a.nw[basew + (int)__popcll(mw & lower)] = n;
}

__device__ __forceinline__ void phase_wq(const MegaArgs& a, int vb, int t) {
  int idx = vb * 256 + t;                     // (l,r,i)
  int i = idx & 127, lr = idx >> 7, l = lr >> 1, r = (lr & 1);
  float aq[4] = {0.f, 0.f, 0.f, 0.f}, ak[4] = {0.f, 0.f, 0.f, 0.f};
  const unsigned short* Wb = a.Wbt + (size_t)lr * HID * HID;
  const float* Qp = a.Qf + l * HID * HEADS;
  const float* Kp = a.Kf + l * HID * HEADS;
  for (int j = 0; j < HID; ++j) {
    float w = bf2f(Wb[j * HID + i]);
    float4 q4 = *(const float4*)(Qp + j * 4);
    float4 k4 = *(const float4*)(Kp + j * 4);
    aq[0] += w * q4.x; aq[1] += w * q4.y; aq[2] += w * q4.z; aq[3] += w * q4.w;
    ak[0] += w * k4.x; ak[1] += w * k4.y; ak[2] += w * k4.z; ak[3] += w * k4.w;
  }
  size_t base = (size_t)l * 16 * HID;
#pragma unroll
  for (int h = 0; h < 4; ++h) {
    unsigned short qh = f2bf_bits(aq[h]);
    unsigned short kh = f2bf_bits(ak[h]);
    float qres = aq[h] - bf2f(qh);
    float kres = ak[h] - bf2f(kh);
    a.qkt_hi[base + (size_t)(r * 4 + h) * HID + i] = qh;
    a.qkt_lo[base + (size_t)(r * 4 + h) * HID + i] = f2bf_bits(qres);
    a.qkt_hi[base + (size_t)(8 + r * 4 + h) * HID + i] = kh;
    a.qkt_lo[base + (size_t)(8 + r * 4 + h) * HID + i] = f2bf_bits(kres);
  }
}

__device__ __forceinline__ void phase_pproj(const MegaArgs& a, int vb, int wave, int lane) {
  const int f0 = a.flags[0];
  int ob = vb * 4 + wave;                     // 0..255
  int o = ob & 127, l = ob >> 7;
  const void* pWraw = l ? a.pW1 : a.pW0;
  const float* cb = a.cbf + l * HID;
  float part = 0.f;
#pragma unroll
  for (int i = lane; i < HID; i += 64) {
    float w = f0 ? ((const float*)pWraw)[o * HID + i] : bf2f(((const unsigned short*)pWraw)[o * HID + i]);
    a.pWTb2[(size_t)l * HID * HID + o * HID + i] = f2bf_bits(w);
    part += cb[i] * w;
  }
#pragma unroll
  for (int off = 32; off > 0; off >>= 1) part += __shfl_xor(part, off);
  if (lane == 0) a.bo2[l * HID + o] = a.pbf[l * HID + o] + part;
}

__device__ __forceinline__ void phase_scan23(const MegaArgs& a, int vb, int t, int* sm) {
  int v = (t < SCAN_B) ? a.bsum[t] : 0;
  sm[t] = v;
  __syncthreads();
#pragma unroll
  for (int off = 1; off < 256; off <<= 1) {
    int add = (t >= off) ? sm[t - off] : 0;
    __syncthreads();
    sm[t] += add;
    __syncthreads();
  }
  int bpre = (vb > 0) ? sm[vb - 1] : 0;
  int i = vb * 256 + t;
  if (i < NPAD) a.rowstart[i] = a.excl[i] + bpre;
  if (i == 0) a.rowstart[NPAD] = E_EDGES;
}

__device__ __forceinline__ void phase_scatter(const MegaArgs& a, int vb, int t) {
  int e = vb * 256 + t;
  if (e < E_EDGES) {
    int d = a.dstA[e];
    int pos = a.rowstart[d] + atomicAdd(&a.cnt[d], 1);
    a.eord[pos] = a.pk[e];
  }
}

// gemm body: As (64 rows bf16 in LDS) @ Wbt[r] -> xw, restaged through Cs.
__device__ __forceinline__ void gemm64_from_lds(unsigned short (*As)[136], unsigned short (*Cs)[136],
                                                const unsigned short* __restrict__ Wbt,
                                                unsigned short* __restrict__ xw, int row0,
                                                int wave, int lm, int q, int t) {
  const int r = wave >> 1, colb = (wave & 1) * 64;
  const unsigned short* Bt = Wbt + (size_t)r * HID * HID;
  s16x8 bfr[4][4];
#pragma unroll
  for (int kc = 0; kc < 4; ++kc) {
    const int ko = kc * 32 + q * 8;
#pragma unroll
    for (int ct = 0; ct < 4; ++ct)
      bfr[kc][ct] = *(const s16x8*)(Bt + (size_t)(colb + ct * 16 + lm) * HID + ko);
  }
  f32x4 acc[4][4];
#pragma unroll
  for (int aa = 0; aa < 4; ++aa)
#pragma unroll
    for (int c = 0; c < 4; ++c) { f32x4 z = {0.f, 0.f, 0.f, 0.f}; acc[aa][c] = z; }
#pragma unroll
  for (int kc = 0; kc < 4; ++kc) {
    const int ko = kc * 32 + q * 8;
#pragma unroll
    for (int rt = 0; rt < 4; ++rt) {
      s16x8 av = *(const s16x8*)&As[rt * 16 + lm][ko];
#pragma unroll
      for (int ct = 0; ct < 4; ++ct)
        acc[rt][ct] = __builtin_amdgcn_mfma_f32_16x16x32_bf16(av, bfr[kc][ct], acc[rt][ct], 0, 0, 0);
    }
  }
  __syncthreads();
#pragma unroll
  for (int rr = 0; rr < 2; ++rr) {
    if (r == rr) {
#pragma unroll
      for (int rt = 0; rt < 4; ++rt)
#pragma unroll
        for (int i = 0; i < 4; ++i) {
          int rloc = rt * 16 + q * 4 + i;
#pragma unroll
          for (int ct = 0; ct < 4; ++ct)
            Cs[rloc][colb + ct * 16 + lm] = f2bf_bits(acc[rt][ct][i]);
        }
    }
    __syncthreads();
    unsigned short* dst = xw + ((size_t)rr * NPAD + row0) * HID;
#pragma unroll
    for (int j = 0; j < 4; ++j) {
      int idx = j * 256 + t;                  // 1024 16B units
      int rw = idx >> 4, cb8 = (idx & 15) * 8;
      if (row0 + rw < N_NODES)
        *(s16x8*)(dst + (size_t)rw * HID + cb8) = *(const s16x8*)&Cs[rw][cb8];
    }
    __syncthreads();
  }
}

// qk body: wave w handles rows [16w,16w+16) of As; writes qi4/kj4.
__device__ __forceinline__ void qk16_from_lds(unsigned short (*As)[136], unsigned short (*Cs)[136],
                                              const unsigned short* __restrict__ qkt_hi,
                                              const unsigned short* __restrict__ qkt_lo,
                                              float4* __restrict__ qi4, float4* __restrict__ kj4,
                                              int row0, int wave, int lane, int lm, int q) {
  s16x8 bhi[4], blo[4], af[4];
#pragma unroll
  for (int kc = 0; kc < 4; ++kc) {
    const int ko = kc * 32 + q * 8;
    bhi[kc] = *(const s16x8*)(qkt_hi + (size_t)lm * HID + ko);
    blo[kc] = *(const s16x8*)(qkt_lo + (size_t)lm * HID + ko);
    af[kc]  = *(const s16x8*)&As[wave * 16 + lm][ko];
  }
  f32x4 acc = {0.f, 0.f, 0.f, 0.f};
#pragma unroll
  for (int kc = 0; kc < 4; ++kc) {
    acc = __builtin_amdgcn_mfma_f32_16x16x32_bf16(af[kc], bhi[kc], acc, 0, 0, 0);
    acc = __builtin_amdgcn_mfma_f32_16x16x32_bf16(af[kc], blo[kc], acc, 0, 0, 0);
  }
  float (*Fs)[16][17] = (float(*)[16][17])&Cs[0][0];
#pragma unroll
  for (int i = 0; i < 4; ++i)
    Fs[wave][lm][q * 4 + i] = acc[i];
  __syncthreads();
  if (lane < 16) {
    int n = row0 + wave * 16 + lane;
    if (n < N_NODES) {
      float4 v;
      v.x = Fs[wave][0][lane];  v.y = Fs[wave][1][lane];  v.z = Fs[wave][2][lane];  v.w = Fs[wave][3][lane];
      qi4[n] = v;
      v.x = Fs[wave][4][lane];  v.y = Fs[wave][5][lane];  v.z = Fs[wave][6][lane];  v.w = Fs[wave][7][lane];
      qi4[NPAD + n] = v;
      v.x = Fs[wave][8][lane];  v.y = Fs[wave][9][lane];  v.z = Fs[wave][10][lane]; v.w = Fs[wave][11][lane];
      kj4[n] = v;
      v.x = Fs[wave][12][lane]; v.y = Fs[wave][13][lane]; v.z = Fs[wave][14][lane]; v.w = Fs[wave][15][lane];
      kj4[NPAD + n] = v;
    }
  }
  __syncthreads();
}

__device__ __forceinline__ void phase_l0(const MegaArgs& a, int vb, int t, int wave, int lane, int lm, int q,
                                         unsigned short (*As)[136], unsigned short (*Cs)[136]) {
  const int row0 = vb * 64;
  if (a.flags[0]) {
    const float* xf = (const float*)a.x;
#pragma unroll
    for (int j = 0; j < 4; ++j) {
      int idx = j * 256 + t;
      int rw = idx >> 4, cb8 = (idx & 15) * 8;
      s16x8 o = {0, 0, 0, 0, 0, 0, 0, 0};
      if (row0 + rw < N_NODES) {
        const float4* s4 = (const float4*)(xf + (size_t)(row0 + rw) * HID + cb8);
        float4 aa = s4[0], b = s4[1];
        o[0] = (short)f2bf_bits(aa.x); o[1] = (short)f2bf_bits(aa.y);
        o[2] = (short)f2bf_bits(aa.z); o[3] = (short)f2bf_bits(aa.w);
        o[4] = (short)f2bf_bits(b.x);  o[5] = (short)f2bf_bits(b.y);
        o[6] = (short)f2bf_bits(b.z);  o[7] = (short)f2bf_bits(b.w);
      }
      *(s16x8*)&As[rw][cb8] = o;
    }
  } else {
    const unsigned short* xb = (const unsigned short*)a.x;
#pragma unroll
    for (int j = 0; j < 4; ++j) {
      int idx = j * 256 + t;
      int rw = idx >> 4, cb8 = (idx & 15) * 8;
      s16x8 o = {0, 0, 0, 0, 0, 0, 0, 0};
      if (row0 + rw < N_NODES)
        o = *(const s16x8*)(xb + (size_t)(row0 + rw) * HID + cb8);
      *(s16x8*)&As[rw][cb8] = o;
    }
  }
  __syncthreads();
  gemm64_from_lds(As, Cs, a.Wbt, a.xw, row0, wave, lm, q, t);
  qk16_from_lds(As, Cs, a.qkt_hi, a.qkt_lo, a.qi4, a.kj4, row0, wave, lane, lm, q);
}

__device__ __forceinline__ void phase_mid(const MegaArgs& a, int vb, int t, int wave, int lane, int lm, int q,
                                          unsigned short (*As)[136], unsigned short (*Cs)[136]) {
  const int row0 = vb * 64;
  const int h = wave >> 1;
  const int colb = (wave & 1) * 64;
  s16x8 bfr[4][4];
#pragma unroll
  for (int kc = 0; kc < 4; ++kc) {
    const int ko = kc * 32 + q * 8;
#pragma unroll
    for (int ct = 0; ct < 4; ++ct)
      bfr[kc][ct] = *(const s16x8*)(a.pWTb2 + (size_t)(colb + ct * 16 + lm) * HID + ko);
  }
  const unsigned short* gsrc = a.aggb + (size_t)row0 * HID;
#pragma unroll
  for (int j = 0; j < 4; ++j) {
    int idx = j * 256 + t;
    *(s16x8*)&As[idx >> 4][(idx & 15) * 8] = *(const s16x8*)(gsrc + idx * 8);
  }
  __syncthreads();
  f32x4 pacc[2][4];
#pragma unroll
  for (int aa = 0; aa < 2; ++aa)
#pragma unroll
    for (int c = 0; c < 4; ++c) { f32x4 z = {0.f, 0.f, 0.f, 0.f}; pacc[aa][c] = z; }
#pragma unroll
  for (int kc = 0; kc < 4; ++kc) {
    const int ko = kc * 32 + q * 8;
#pragma unroll
    for (int rt = 0; rt < 2; ++rt) {
      s16x8 av = *(const s16x8*)&As[(2 * h + rt) * 16 + lm][ko];
#pragma unroll
      for (int ct = 0; ct < 4; ++ct)
        pacc[rt][ct] = __builtin_amdgcn_mfma_f32_16x16x32_bf16(av, bfr[kc][ct], pacc[rt][ct], 0, 0, 0);
    }
  }
  __syncthreads();
#pragma unroll
  for (int rt = 0; rt < 2; ++rt)
#pragma unroll
    for (int i = 0; i < 4; ++i) {
      int rloc = (2 * h + rt) * 16 + q * 4 + i;
#pragma unroll
      for (int ct = 0; ct < 4; ++ct) {
        int o = colb + ct * 16 + lm;
        As[rloc][o] = f2bf_bits(elu(pacc[rt][ct][i] + a.bo2[o]));
      }
    }
  __syncthreads();
  const unsigned short* Wbt1 = a.Wbt + (size_t)2 * HID * HID;
  gemm64_from_lds(As, Cs, Wbt1, a.xw, row0, wave, lm, q, t);
  qk16_from_lds(As, Cs, a.qkt_hi + (size_t)16 * HID, a.qkt_lo + (size_t)16 * HID,
                a.qi4, a.kj4, row0, wave, lane, lm, q);
}

__device__ __forceinline__ void phase_final(const MegaArgs& a, int vb, int t, int wave, int lane, int lm, int q,
                                            unsigned short (*As)[136]) {
  const int row0 = vb * 64;
  const int h = wave >> 1;
  const int colb = (wave & 1) * 64;
  const unsigned short* pWT1 = a.pWTb2 + (size_t)HID * HID;
  const float* bo1 = a.bo2 + HID;
  s16x8 bfr[4][4];
#pragma unroll
  for (int kc = 0; kc < 4; ++kc) {
    const int ko = kc * 32 + q * 8;
#pragma unroll
    for (int ct = 0; ct < 4; ++ct)
      bfr[kc][ct] = *(const s16x8*)(pWT1 + (size_t)(colb + ct * 16 + lm) * HID + ko);
  }
  const unsigned short* gsrc = a.aggb + (size_t)row0 * HID;
#pragma unroll
  for (int j = 0; j < 4; ++j) {
    int idx = j * 256 + t;
    *(s16x8*)&As[idx >> 4][(idx & 15) * 8] = *(const s16x8*)(gsrc + idx * 8);
  }
  __syncthreads();
  f32x4 acc[2][4];
#pragma unroll
  for (int aa = 0; aa < 2; ++aa)
#pragma unroll
    for (int c = 0; c < 4; ++c) { f32x4 z = {0.f, 0.f, 0.f, 0.f}; acc[aa][c] = z; }
#pragma unroll
  for (int kc = 0; kc < 4; ++kc) {
    const int ko = kc * 32 + q * 8;
#pragma unroll
    for (int rt = 0; rt < 2; ++rt) {
      s16x8 av = *(const s16x8*)&As[(2 * h + rt) * 16 + lm][ko];
#pragma unroll
      for (int ct = 0; ct < 4; ++ct)
        acc[rt][ct] = __builtin_amdgcn_mfma_f32_16x16x32_bf16(av, bfr[kc][ct], acc[rt][ct], 0, 0, 0);
    }
  }
  __syncthreads();
  if (!a.flags[0]) {
    unsigned short* dstp = (unsigned short*)a.dout;
#pragma unroll
    for (int rt = 0; rt < 2; ++rt)
#pragma unroll
      for (int i = 0; i < 4; ++i) {
        int rloc = (2 * h + rt) * 16 + q * 4 + i;
#pragma unroll
        for (int ct = 0; ct < 4; ++ct) {
          int o = colb + ct * 16 + lm;
          As[rloc][o] = f2bf_bits(elu(acc[rt][ct][i] + bo1[o]));
        }
      }
    __syncthreads();
#pragma unroll
    for (int j = 0; j < 4; ++j) {
      int idx = j * 256 + t;
      int rw = idx >> 4, cb8 = (idx & 15) * 8;
      if (row0 + rw < N_NODES)
        *(s16x8*)(dstp + (size_t)(row0 + rw) * HID + cb8) = *(const s16x8*)&As[rw][cb8];
    }
    __syncthreads();
  } else {
    float* fdst = (float*)a.dout;
    float (*Fs)[132] = (float(*)[132])&As[0][0];   // 32*132*4 = 16896 B
#pragma unroll
    for (int h2 = 0; h2 < 2; ++h2) {
      if (h == h2) {
#pragma unroll
        for (int rt = 0; rt < 2; ++rt)
#pragma unroll
          for (int i = 0; i < 4; ++i) {
            int rloc = rt * 16 + q * 4 + i;
#pragma unroll
            for (int ct = 0; ct < 4; ++ct) {
              int o = colb + ct * 16 + lm;
              Fs[rloc][o] = elu(acc[rt][ct][i] + bo1[o]);
            }
          }
      }
      __syncthreads();
#pragma unroll
      for (int j = 0; j < 4; ++j) {
        int idx = j * 256 + t;
        int rw = idx >> 5, cb4 = (idx & 31) * 4;
        if (row0 + h2 * 32 + rw < N_NODES)
          *(float4*)(fdst + (size_t)(row0 + h2 * 32 + rw) * HID + cb4) = *(const float4*)&Fs[rw][cb4];
      }
      __syncthreads();
    }
  }
}

// edge body: big range [0,NBIG) grid-strides over actual count; quad at [NBIG,..)
__device__ __forceinline__ void edge_vb(const MegaArgs& a, int vb, volatile float* wbuf,
                                        int wave, int lane) {
  const float4* qi4 = a.qi4;
  const float4* kj4 = a.kj4;
  const unsigned short* xw = a.xw;
  if (vb >= NBIG) {
    // ---- quad: 4 nodes/wave, 16 lanes/node, 8 ch/lane; single 16-wide gather ----
    const int g = lane >> 4, li = lane & 15;
    const int idx = (vb - NBIG) * 16 + wave * 4 + g;
    const int cq = a.bcnt[0];
    const bool act = idx < cq;
    const int n = act ? a.nq[idx] : 0;
    const int start = a.rowstart[n];
    const int dg = act ? (a.rowstart[n + 1] - start) : 0;
    int p = 0;
    float w0 = 0.f, w1 = 0.f, w2 = 0.f, w3 = 0.f;
    if (li < dg) {
      p = a.eord[start + li];
      int s = p & 0xffff, r = p >> 16;
      float4 k4 = kj4[r ? (NPAD + s) : s];
      float4 q4 = r ? qi4[NPAD + n] : qi4[n];
      w0 = __expf(fminf(lrelu(q4.x + k4.x), 85.f));
      w1 = __expf(fminf(lrelu(q4.y + k4.y), 85.f));
      w2 = __expf(fminf(lrelu(q4.z + k4.z), 85.f));
      w3 = __expf(fminf(lrelu(q4.w + k4.w), 85.f));
    }
    const int wg = (wave << 2) | g;
    volatile float* wls = &wbuf[wg * 68];     // [4][17]
    wls[0 * 17 + li] = w0; wls[1 * 17 + li] = w1;
    wls[2 * 17 + li] = w2; wls[3 * 17 + li] = w3;
    float s0 = w0, s1 = w1, s2 = w2, s3 = w3;
#pragma unroll
    for (int off = 8; off > 0; off >>= 1) {
      s0 += __shfl_xor(s0, off); s1 += __shfl_xor(s1, off);
      s2 += __shfl_xor(s2, off); s3 += __shfl_xor(s3, off);
    }
    const int hh = li >> 2;
    float ssel = hh == 0 ? s0 : hh == 1 ? s1 : hh == 2 ? s2 : s3;
    float a0 = 0.f, a1 = 0.f, a2 = 0.f, a3 = 0.f, a4 = 0.f, a5 = 0.f, a6 = 0.f, a7 = 0.f;
    volatile const float* wrh = &wls[hh * 17];
    const int co = li * 8;
    const int gbase = lane & 48;
    if (dg > 0) {
      // deg<=16 by construction: ONE fully-unrolled batch, 16 loads in flight
      int pe[16];
      uint4 v[16];
#pragma unroll
      for (int u = 0; u < 16; ++u)
        pe[u] = __shfl(p, gbase + (u < dg ? u : 0));
#pragma unroll
      for (int u = 0; u < 16; ++u)
        v[u] = *(const uint4*)(xw + ((size_t)((pe[u] & 0xffff) + (pe[u] >> 16) * NPAD) << 7) + co);
#pragma unroll
      for (int u = 0; u < 16; ++u) {
        float we = (u < dg) ? wrh[u] : 0.f;
        a0 = fmaf(lo_f(v[u].x), we, a0); a1 = fmaf(hi_f(v[u].x), we, a1);
        a2 = fmaf(lo_f(v[u].y), we, a2); a3 = fmaf(hi_f(v[u].y), we, a3);
        a4 = fmaf(lo_f(v[u].z), we, a4); a5 = fmaf(hi_f(v[u].z), we, a5);
        a6 = fmaf(lo_f(v[u].w), we, a6); a7 = fmaf(hi_f(v[u].w), we, a7);
      }
    }
    if (act) {
      float inv = 1.f / (ssel + 1e-16f);
      uint4 o;
      o.x = (unsigned)f2bf_bits(a0 * inv) | ((unsigned)f2bf_bits(a1 * inv) << 16);
      o.y = (unsigned)f2bf_bits(a2 * inv) | ((unsigned)f2bf_bits(a3 * inv) << 16);
      o.z = (unsigned)f2bf_bits(a4 * inv) | ((unsigned)f2bf_bits(a5 * inv) << 16);
      o.w = (unsigned)f2bf_bits(a6 * inv) | ((unsigned)f2bf_bits(a7 * inv) << 16);
      *(uint4*)(a.aggb + ((size_t)n << 7) + co) = o;
    }
  } else {
    // ---- big: one wave per node, grid-stride over actual count ----
    const int cw = a.bcnt[1];
    for (int idx = vb * 4 + wave; idx < cw; idx += NBIG * 4) {
      const int n = a.nw[idx];
      unsigned* outp = (unsigned*)(a.aggb + ((size_t)n << 7)) + lane;
      const int start = a.rowstart[n];
      const int deg = a.rowstart[n + 1] - start;
      const int hh = lane >> 4;
      const int ch2 = lane << 1;
      float2 acc = {0.f, 0.f};
      float ssel;
      volatile float* wls = &wbuf[wave * 288];  // [4][72]
      if (deg <= 64) {
        int p = 0;
        float w0 = 0.f, w1 = 0.f, w2 = 0.f, w3 = 0.f;
        if (lane < deg) {
          p = a.eord[start + lane];
          int s = p & 0xffff, r = p >> 16;
          float4 k4 = kj4[r ? (NPAD + s) : s];
          float4 q4 = r ? qi4[NPAD + n] : qi4[n];
          w0 = __expf(fminf(lrelu(q4.x + k4.x), 85.f));
          w1 = __expf(fminf(lrelu(q4.y + k4.y), 85.f));
          w2 = __expf(fminf(lrelu(q4.z + k4.z), 85.f));
          w3 = __expf(fminf(lrelu(q4.w + k4.w), 85.f));
        }
        float s0 = w0, s1 = w1, s2 = w2, s3 = w3;
#pragma unroll
        for (int off = 32; off > 0; off >>= 1) {
          s0 += __shfl_xor(s0, off); s1 += __shfl_xor(s1, off);
          s2 += __shfl_xor(s2, off); s3 += __shfl_xor(s3, off);
        }
        ssel = hh == 0 ? s0 : hh == 1 ? s1 : hh == 2 ? s2 : s3;
        wls[0 * 72 + lane] = w0;
        wls[1 * 72 + lane] = w1;
        wls[2 * 72 + lane] = w2;
        wls[3 * 72 + lane] = w3;
        volatile const float* wrh = &wls[hh * 72];
        const int degp = (deg + 15) & ~15;
#pragma unroll 1
        for (int e = 0; e < degp; e += 16) {
          int pp[16];
          unsigned vv[16];
#pragma unroll
          for (int u = 0; u < 16; ++u)
            pp[u] = __builtin_amdgcn_readlane(p, e + u);
#pragma unroll
          for (int u = 0; u < 16; ++u)
            vv[u] = *(const unsigned*)(xw + ((size_t)((pp[u] & 0xffff) + (pp[u] >> 16) * NPAD) << 7) + ch2);
#pragma unroll
          for (int u = 0; u < 16; ++u) {
            float we = wrh[e + u];
            acc.x = fmaf(lo_f(vv[u]), we, acc.x);
            acc.y = fmaf(hi_f(vv[u]), we, acc.y);
          }
        }
      } else {
        const float4 q0 = qi4[n], q1 = qi4[NPAD + n];
        float4 m = make_float4(-1e30f, -1e30f, -1e30f, -1e30f);
        for (int e = start; e < start + deg; ++e) {
          int pe = a.eord[e];
          int s = pe & 0xffff, r = pe >> 16;
          float4 k4 = kj4[(size_t)r * NPAD + s];
          float4 q4 = r ? q1 : q0;
          m.x = fmaxf(m.x, lrelu(q4.x + k4.x)); m.y = fmaxf(m.y, lrelu(q4.y + k4.y));
          m.z = fmaxf(m.z, lrelu(q4.z + k4.z)); m.w = fmaxf(m.w, lrelu(q4.w + k4.w));
        }
        float4 sv = make_float4(0.f, 0.f, 0.f, 0.f);
        for (int e = start; e < start + deg; ++e) {
          int pe = a.eord[e];
          int s = pe & 0xffff, r = pe >> 16;
          float4 k4 = kj4[(size_t)r * NPAD + s];
          float4 q4 = r ? q1 : q0;
          float w0 = __expf(lrelu(q4.x + k4.x) - m.x);
          float w1 = __expf(lrelu(q4.y + k4.y) - m.y);
          float w2 = __expf(lrelu(q4.z + k4.z) - m.z);
          float w3 = __expf(lrelu(q4.w + k4.w) - m.w);
          sv.x += w0; sv.y += w1; sv.z += w2; sv.w += w3;
          float we = hh == 0 ? w0 : hh == 1 ? w1 : hh == 2 ? w2 : w3;
          unsigned v = *(const unsigned*)(xw + (((size_t)r * NPAD + s) << 7) + ch2);
          acc.x = fmaf(lo_f(v), we, acc.x);
          acc.y = fmaf(hi_f(v), we, acc.y);
        }
        ssel = hh == 0 ? sv.x : hh == 1 ? sv.y : hh == 2 ? sv.z : sv.w;
      }
      float inv = 1.f / (ssel + 1e-16f);
      *outp = (unsigned)f2bf_bits(acc.x * inv) | ((unsigned)f2bf_bits(acc.y * inv) << 16);
    }
  }
}

// ====== dispatch kernels ======
__global__ __launch_bounds__(256) void k_zero(MegaArgs a) {
  __shared__ int dcnt[2];
  phase_zero(a, blockIdx.x, threadIdx.x);
  if (blockIdx.x == 0) phase_detect(a, threadIdx.x, dcnt);
}
__global__ __launch_bounds__(256) void k_cvt(MegaArgs a) {
  phase_cvt(a, blockIdx.x, threadIdx.x);
}
// scan1 | bucket | prep_wq | prep_proj fused by block range
__global__ __launch_bounds__(256) void k_s1prep(MegaArgs a) {
  __shared__ int sm[256];
  const int b = blockIdx.x, t = threadIdx.x;
  if (b < SCAN_B)                phase_scan1(a, b, t, sm);
  else if (b < 2 * SCAN_B)       phase_bucket(a, b - SCAN_B, t, t & 63);
  else if (b < 2 * SCAN_B + 2)   phase_wq(a, b - 2 * SCAN_B, t);
  else                           phase_pproj(a, b - 2 * SCAN_B - 2, t >> 6, t & 63);
}
__global__ __launch_bounds__(256) void k_scan23(MegaArgs a) {
  __shared__ int sm[256];
  phase_scan23(a, blockIdx.x, threadIdx.x, sm);
}
// l0 (blocks [0,VB_ROWS)) || scatter (blocks [VB_ROWS, +VB_SCAT)) — independent chains
__global__ __launch_bounds__(256) void k_scat_l0(MegaArgs a) {
  __shared__ unsigned short As[64][136];
  __shared__ unsigned short Cs[64][136];
  const int b = blockIdx.x, t = threadIdx.x;
  if (b < VB_ROWS) {
    const int wave = t >> 6, lane = t & 63;
    phase_l0(a, b, t, wave, lane, lane & 15, lane >> 4, As, Cs);
  } else {
    phase_scatter(a, b - VB_ROWS, t);
  }
}
__global__ __launch_bounds__(256) void k_edge(MegaArgs a) {
  __shared__ volatile float wbuf[1152];
  edge_vb(a, blockIdx.x, wbuf, threadIdx.x >> 6, threadIdx.x & 63);
}
__global__ __launch_bounds__(256) void k_mid(MegaArgs a) {
  __shared__ unsigned short As[64][136];
  __shared__ unsigned short Cs[64][136];
  const int t = threadIdx.x, wave = t >> 6, lane = t & 63;
  phase_mid(a, blockIdx.x, t, wave, lane, lane & 15, lane >> 4, As, Cs);
}
__global__ __launch_bounds__(256) void k_final(MegaArgs a) {
  __shared__ unsigned short As[64][136];
  const int t = threadIdx.x, wave = t >> 6, lane = t & 63;
  phase_final(a, blockIdx.x, t, wave, lane, lane & 15, lane >> 4, As);
}

extern "C" void kernel_launch(void* const* d_in, const int* in_sizes, int n_in,
                              void* d_out, int out_size, void* d_ws, size_t ws_size,
                              hipStream_t stream) {
  const int iW[2] = {3, 9}, iQ[2] = {4, 10}, iK[2] = {5, 11}, icb[2] = {6, 12}, ipW[2] = {7, 13}, ipb[2] = {8, 14};

  float* ws = (float*)d_ws;
  size_t off = 0;
  int*   flags = (int*)(ws + off); off += 16;
  unsigned short* xw   = (unsigned short*)(ws + off); off += (size_t)NPAD * HID;       // [2][NPAD][128] bf16
  float* qi   = ws + off; off += (size_t)2 * NPAD * HEADS;
  float* kj   = ws + off; off += (size_t)2 * NPAD * HEADS;
  unsigned short* aggb = (unsigned short*)(ws + off); off += (size_t)NPAD * HID / 2;
  int* dstA = (int*)(ws + off); off += E_EDGES;
  int* pk   = (int*)(ws + off); off += E_EDGES;
  int* eord = (int*)(ws + off); off += E_EDGES;
  int* deg  = (int*)(ws + off); off += NPAD;        // deg|cnt|bcnt contiguous for one zero pass
  int* cnt  = (int*)(ws + off); off += NPAD;
  int* bcnt = (int*)(ws + off); off += 16;
  int* excl = (int*)(ws + off); off += NPAD;
  int* rowstart = (int*)(ws + off); off += NPAD + 16;
  int* bsum  = (int*)(ws + off); off += 256;
  int* nq   = (int*)(ws + off); off += NPAD;
  int* nwl  = (int*)(ws + off); off += NPAD;
  unsigned short* Wbt   = (unsigned short*)(ws + off); off += (size_t)2 * 2 * HID * HID / 2;
  unsigned short* pWTb2 = (unsigned short*)(ws + off); off += (size_t)2 * HID * HID / 2;
  unsigned short* qkt_hi = (unsigned short*)(ws + off); off += (size_t)2 * 16 * HID / 2;
  unsigned short* qkt_lo = (unsigned short*)(ws + off); off += (size_t)2 * 16 * HID / 2;
  float* Qf  = ws + off; off += 2 * HID * HEADS;
  float* Kf  = ws + off; off += 2 * HID * HEADS;
  float* cbf = ws + off; off += 2 * HID;
  float* pbf = ws + off; off += 2 * HID;
  float* bo2 = ws + off; off += 2 * HID;

  MegaArgs a;
  a.x = d_in[0]; a.eidx = (const int*)d_in[1]; a.etype = (const int*)d_in[2];
  a.w0 = d_in[iW[0]]; a.w1 = d_in[iW[1]]; a.pW0 = d_in[ipW[0]]; a.pW1 = d_in[ipW[1]];
  for (int l = 0; l < 2; ++l) {
    a.tab.src[l * 4 + 0] = d_in[iQ[l]];  a.tab.dstoff[l * 4 + 0] = (int)(Qf - ws) + l * HID * HEADS;  a.tab.n[l * 4 + 0] = HID * HEADS;
    a.tab.src[l * 4 + 1] = d_in[iK[l]];  a.tab.dstoff[l * 4 + 1] = (int)(Kf - ws) + l * HID * HEADS;  a.tab.n[l * 4 + 1] = HID * HEADS;
    a.tab.src[l * 4 + 2] = d_in[icb[l]]; a.tab.dstoff[l * 4 + 2] = (int)(cbf - ws) + l * HID;         a.tab.n[l * 4 + 2] = HID;
    a.tab.src[l * 4 + 3] = d_in[ipb[l]]; a.tab.dstoff[l * 4 + 3] = (int)(pbf - ws) + l * HID;         a.tab.n[l * 4 + 3] = HID;
  }
  a.base = ws;
  a.flags = flags; a.xw = xw; a.qi4 = (float4*)qi; a.kj4 = (float4*)kj; a.aggb = aggb;
  a.dstA = dstA; a.pk = pk; a.eord = eord; a.deg = deg; a.cnt = cnt; a.bcnt = bcnt;
  a.excl = excl; a.rowstart = rowstart; a.bsum = bsum; a.nq = nq; a.nw = nwl;
  a.Wbt = Wbt; a.pWTb2 = pWTb2; a.qkt_hi = qkt_hi; a.qkt_lo = qkt_lo;
  a.Qf = Qf; a.Kf = Kf; a.cbf = cbf; a.pbf = pbf; a.bo2 = bo2;
  a.dout = d_out;

  // 9-dispatch chain; scatter overlapped with layer-0 compute (independent deps)
  k_zero<<<VB_ZERO, 256, 0, stream>>>(a);
  k_cvt<<<VB_CVT, 256, 0, stream>>>(a);
  k_s1prep<<<2 * SCAN_B + 2 + 64, 256, 0, stream>>>(a);
  k_scan23<<<SCAN_B, 256, 0, stream>>>(a);
  k_scat_l0<<<VB_ROWS + VB_SCAT, 256, 0, stream>>>(a);
  k_edge<<<VB_EDGE, 256, 0, stream>>>(a);
  k_mid<<<VB_ROWS, 256, 0, stream>>>(a);
  k_edge<<<VB_EDGE, 256, 0, stream>>>(a);
  k_final<<<VB_ROWS, 256, 0, stream>>>(a);
}